// Round 9
// baseline (878.852 us; speedup 1.0000x reference)
//
#include <hip/hip_runtime.h>
#include <hip/hip_bf16.h>

#define NN 100000
#define NE 3200000
#define D 64
#define BN_EPS 1e-5f

#define NP 512       // producer blocks
#define CHUNK 6250   // edges per producer (512*6250 = 3.2M exactly)
#define NB 391       // dst buckets of 256 nodes (391*256 = 100096 >= NN)

typedef __hip_bfloat16 bf16;

// unpack 2 packed bf16 (lo=dim2l, hi=dim2l+1) to floats
__device__ __forceinline__ float2 bf2_to_f2(unsigned u) {
  union { unsigned ui; float f; } a, b;
  a.ui = u << 16;
  b.ui = u & 0xffff0000u;
  return make_float2(a.f, b.f);
}

// ---- embedding gather: zcat[:,0:64] = embed_deg[node_deg]; mirror to xh ----
__global__ __launch_bounds__(256) void embed_kernel(const int* __restrict__ deg,
    const float* __restrict__ emb, float* __restrict__ zcat,
    bf16* __restrict__ xh) {
  int idx = blockIdx.x * 256 + threadIdx.x;
  int i = idx >> 6, d = idx & 63;
  if (i < NN) {
    float v = emb[(long)deg[i] * D + d];
    zcat[(long)i * 256 + d] = v;
    xh[(long)(d >> 5) * NN * 32 + (long)i * 32 + (d & 31)] = __float2bfloat16(v);
  }
}

// ---- producer: bucket edges into private per-block regions (packed records)
__global__ __launch_bounds__(256) void bucket_kernel(const int* __restrict__ ei,
    int* __restrict__ rec, int* __restrict__ S) {
  __shared__ int cntL[392];
  __shared__ int curL[392];
  __shared__ int scanbuf[256];
  int t = threadIdx.x;
  int p = blockIdx.x;
  int e0 = p * CHUNK;
  cntL[t] = 0;
  if (t < 136) cntL[256 + t] = 0;
  __syncthreads();
  for (int e = t; e < CHUNK; e += 256) {
    int dd = ei[NE + e0 + e];
    atomicAdd(&cntL[(unsigned)dd >> 8], 1);
  }
  __syncthreads();
  int a0 = 0, a1 = 0;
  if (t < 196) { a0 = cntL[2 * t]; a1 = cntL[2 * t + 1]; }
  int s = a0 + a1;
  scanbuf[t] = s;
  __syncthreads();
  for (int off = 1; off < 256; off <<= 1) {
    int x = (t >= off) ? scanbuf[t - off] : 0;
    __syncthreads();
    scanbuf[t] += x;
    __syncthreads();
  }
  int ex = scanbuf[t] - s;
  if (t < 196) {
    curL[2 * t]     = ex;
    curL[2 * t + 1] = ex + a0;
    S[p * 392 + 2 * t]     = e0 + ex;
    S[p * 392 + 2 * t + 1] = e0 + ex + a0;
  }
  __syncthreads();
  for (int e = t; e < CHUNK; e += 256) {
    int ss = ei[e0 + e];
    int dd = ei[NE + e0 + e];
    int b = (unsigned)dd >> 8;
    int pos = atomicAdd(&curL[b], 1);
    rec[e0 + pos] = ss | ((dd & 255) << 17);
  }
}

// ---- bucket totals: bsum[B] = sum_p (S[p][B+1]-S[p][B]) ----
__global__ __launch_bounds__(256) void bucketsum_kernel(const int* __restrict__ S,
    int* __restrict__ bsum) {
  __shared__ int sh[256];
  int B = blockIdx.x;
  int t = threadIdx.x;
  int c = 0;
  for (int p = t; p < NP; p += 256)
    c += S[p * 392 + B + 1] - S[p * 392 + B];
  sh[t] = c;
  __syncthreads();
  for (int o = 128; o > 0; o >>= 1) {
    if (t < o) sh[t] += sh[t + o];
    __syncthreads();
  }
  if (t == 0) bsum[B] = sh[0];
}

// ---- exclusive scan of 391 bucket totals ----
__global__ __launch_bounds__(512) void scan2_kernel(int* __restrict__ bsum) {
  __shared__ int sh[512];
  int t = threadIdx.x;
  int v = (t < NB) ? bsum[t] : 0;
  sh[t] = v;
  __syncthreads();
  for (int o = 1; o < 512; o <<= 1) {
    int x = (t >= o) ? sh[t - o] : 0;
    __syncthreads();
    sh[t] += x;
    __syncthreads();
  }
  if (t < NB) bsum[t] = sh[t] - v;
}

// ---- sorter: one block per bucket, 512 threads, 16-lane segment groups ----
__global__ __launch_bounds__(512) void sort_kernel(const int* __restrict__ rec,
    const int* __restrict__ S, const int* __restrict__ bsum,
    int* __restrict__ csroff, int* __restrict__ csrsrc) {
  __shared__ int cntL[256];
  __shared__ int curL[256];
  int t = threadIdx.x;
  int B = blockIdx.x;
  if (t < 256) cntL[t] = 0;
  __syncthreads();
  int lane = t & 15;
  int g = t >> 4;
  for (int p = g; p < NP; p += 32) {
    int s0 = S[p * 392 + B], s1 = S[p * 392 + B + 1];
    for (int e = s0 + lane; e < s1; e += 16)
      atomicAdd(&cntL[(unsigned)rec[e] >> 17], 1);
  }
  __syncthreads();
  int v = 0;
  if (t < 256) { v = cntL[t]; curL[t] = v; }
  __syncthreads();
  for (int o = 1; o < 256; o <<= 1) {
    int x = 0;
    if (t < 256 && t >= o) x = curL[t - o];
    __syncthreads();
    if (t < 256) curL[t] += x;
    __syncthreads();
  }
  int b0 = bsum[B];
  if (t < 256) {
    int excl = curL[t] - v;
    int node = B * 256 + t;
    if (node <= NN) csroff[node] = b0 + excl;
  }
  __syncthreads();
  if (t < 256) curL[t] = b0 + (curL[t] - v);
  __syncthreads();
  for (int p = g; p < NP; p += 32) {
    int s0 = S[p * 392 + B], s1 = S[p * 392 + B + 1];
    for (int e = s0 + lane; e < s1; e += 16) {
      int r = rec[e];
      int pos = atomicAdd(&curL[(unsigned)r >> 17], 1);
      csrsrc[pos] = r & 0x1FFFF;
    }
  }
}

// ---- aggregation, one 32-dim half per dispatch (L2 working set 6.4 MB) ----
// 16-lane group per node; lane handles dims (2l, 2l+1) of the half via uint load.
__global__ __launch_bounds__(256) void agg_kernel(const int* __restrict__ off,
    const int* __restrict__ srcs, const unsigned* __restrict__ xh32,
    float* __restrict__ agg, int h) {
  int t = threadIdx.x;
  int lane = t & 15;
  int g = t >> 4;                 // 16 groups/block
  int i = blockIdx.x * 16 + g;    // grid 6250 -> exact
  int e0 = off[i], e1 = off[i + 1];
  float s0 = 0.0f, s1 = 0.0f;
  int e = e0;
  for (; e + 4 <= e1; e += 4) {
    int j0 = srcs[e + 0], j1 = srcs[e + 1], j2 = srcs[e + 2], j3 = srcs[e + 3];
    unsigned u0 = xh32[(long)j0 * 16 + lane];
    unsigned u1 = xh32[(long)j1 * 16 + lane];
    unsigned u2 = xh32[(long)j2 * 16 + lane];
    unsigned u3 = xh32[(long)j3 * 16 + lane];
    float2 f0 = bf2_to_f2(u0), f1 = bf2_to_f2(u1);
    float2 f2 = bf2_to_f2(u2), f3 = bf2_to_f2(u3);
    s0 += (f0.x + f1.x) + (f2.x + f3.x);
    s1 += (f0.y + f1.y) + (f2.y + f3.y);
  }
  for (; e < e1; e++) {
    float2 f = bf2_to_f2(xh32[(long)srcs[e] * 16 + lane]);
    s0 += f.x; s1 += f.y;
  }
  *(float2*)&agg[(long)i * D + h * 32 + 2 * lane] = make_float2(s0, s1);
}

// ---- 64-col tiled GEMM, strided X/Y, K in {64,256}: 4x4 reg tile/thread ----
__global__ __launch_bounds__(256) void gemm64_kernel(
    const float* __restrict__ X, int xstride, int K,
    const float* __restrict__ AGG, const float* __restrict__ epsv, int l,
    const float* __restrict__ W, const float* __restrict__ bias,
    float* Y, int ystride, int leaky)
{
  __shared__ float Ws[64][64];     // Ws[k][d]
  __shared__ float XsT[64][64];    // XsT[k][row]
  int t = threadIdx.x;
  int i0 = blockIdx.x * 64;
  float alpha = (AGG != nullptr) ? (1.0f + epsv[l]) : 1.0f;

  int c0 = (t & 15) * 4;
  int r0 = (t >> 4) * 4;
  float4 b4 = *(const float4*)&bias[c0];
  float4 acc[4];
  #pragma unroll
  for (int r = 0; r < 4; r++) acc[r] = b4;

  for (int kc = 0; kc < K; kc += 64) {
    __syncthreads();
    {
      int wr = t >> 4;
      int wc = (t & 15) * 4;
      #pragma unroll
      for (int j = 0; j < 4; j++) {
        float4 w4 = *(const float4*)&W[(long)(kc + wr + 16 * j) * D + wc];
        *(float4*)&Ws[wr + 16 * j][wc] = w4;
      }
    }
    {
      int row = t & 63;
      int gi = i0 + row;
      int gis = (gi < NN) ? gi : NN - 1;
      int kb = (t >> 6) * 16;
      #pragma unroll
      for (int j = 0; j < 4; j++) {
        int k = kb + 4 * j;
        float4 xv = *(const float4*)&X[(long)gis * xstride + kc + k];
        if (AGG) {
          float4 a4 = *(const float4*)&AGG[(long)gis * D + k];
          xv.x = alpha * xv.x + a4.x;
          xv.y = alpha * xv.y + a4.y;
          xv.z = alpha * xv.z + a4.z;
          xv.w = alpha * xv.w + a4.w;
        }
        XsT[k + 0][row] = xv.x;
        XsT[k + 1][row] = xv.y;
        XsT[k + 2][row] = xv.z;
        XsT[k + 3][row] = xv.w;
      }
    }
    __syncthreads();

    #pragma unroll 8
    for (int k = 0; k < 64; k++) {
      float4 w4 = *(const float4*)&Ws[k][c0];
      float4 x4 = *(const float4*)&XsT[k][r0];
      acc[0].x += x4.x * w4.x; acc[0].y += x4.x * w4.y;
      acc[0].z += x4.x * w4.z; acc[0].w += x4.x * w4.w;
      acc[1].x += x4.y * w4.x; acc[1].y += x4.y * w4.y;
      acc[1].z += x4.y * w4.z; acc[1].w += x4.y * w4.w;
      acc[2].x += x4.z * w4.x; acc[2].y += x4.z * w4.y;
      acc[2].z += x4.z * w4.z; acc[2].w += x4.z * w4.w;
      acc[3].x += x4.w * w4.x; acc[3].y += x4.w * w4.y;
      acc[3].z += x4.w * w4.z; acc[3].w += x4.w * w4.w;
    }
  }

  #pragma unroll
  for (int r = 0; r < 4; r++) {
    int gi = i0 + r0 + r;
    if (gi < NN) {
      float4 v = acc[r];
      if (leaky) {
        v.x = (v.x >= 0.0f) ? v.x : 0.01f * v.x;
        v.y = (v.y >= 0.0f) ? v.y : 0.01f * v.y;
        v.z = (v.z >= 0.0f) ? v.z : 0.01f * v.z;
        v.w = (v.w >= 0.0f) ? v.w : 0.01f * v.w;
      }
      *(float4*)&Y[(long)gi * ystride + c0] = v;
    }
  }
}

// ---- BN stats (strided) ----
__global__ __launch_bounds__(256) void bn_stats_kernel(const float* __restrict__ Y,
    int ystride, float* __restrict__ stats) {
  int tid = threadIdx.x;
  int d = tid & 63, q = tid >> 6;
  float s = 0.0f, ss = 0.0f;
  for (int i = blockIdx.x * 4 + q; i < NN; i += gridDim.x * 4) {
    float v = Y[(long)i * ystride + d];
    s += v;
    ss += v * v;
  }
  __shared__ float Ss[4][64], SSs[4][64];
  Ss[q][d] = s; SSs[q][d] = ss;
  __syncthreads();
  if (q == 0) {
    s  = Ss[0][d] + Ss[1][d] + Ss[2][d] + Ss[3][d];
    ss = SSs[0][d] + SSs[1][d] + SSs[2][d] + SSs[3][d];
    atomicAdd(&stats[d], s);
    atomicAdd(&stats[64 + d], ss);
  }
}

// ---- BN apply + leaky (strided, optional bf16 half-split mirror) ----
__global__ __launch_bounds__(256) void bn_apply_kernel(const float* __restrict__ Y,
    int ystride, const float* __restrict__ stats,
    const float* __restrict__ g, const float* __restrict__ b,
    float* __restrict__ Out, bf16* __restrict__ Outh) {
  int idx = blockIdx.x * 256 + threadIdx.x;
  int i = idx >> 6, d = idx & 63;
  if (i >= NN) return;
  float invn = 1.0f / (float)NN;
  float mu = stats[d] * invn;
  float var = fmaxf(stats[64 + d] * invn - mu * mu, 0.0f);
  float sc = g[d] * rsqrtf(var + BN_EPS);
  float v = sc * (Y[(long)i * ystride + d] - mu) + b[d];
  v = (v >= 0.0f) ? v : 0.01f * v;
  Out[(long)i * ystride + d] = v;
  if (Outh)
    Outh[(long)(d >> 5) * NN * 32 + (long)i * 32 + (d & 31)] = __float2bfloat16(v);
}

// ---- fc2 ----
__global__ __launch_bounds__(256) void fc2_kernel(const float* __restrict__ H,
    const float* __restrict__ W, const float* __restrict__ b,
    float* __restrict__ out) {
  int tid = threadIdx.x;
  int k = tid & 63, q = tid >> 6;
  int i = blockIdx.x * 4 + q;
  float v = (i < NN) ? H[(long)i * D + k] * W[k] : 0.0f;
  #pragma unroll
  for (int off = 32; off > 0; off >>= 1)
    v += __shfl_down(v, off);
  if (k == 0 && i < NN) {
    float x = v + b[0];
    out[i] = 1.0f / (1.0f + __expf(-x));
  }
}

extern "C" void kernel_launch(void* const* d_in, const int* in_sizes, int n_in,
                              void* d_out, int out_size, void* d_ws, size_t ws_size,
                              hipStream_t stream) {
  const int*   node_deg   = (const int*)d_in[0];
  const int*   edge_index = (const int*)d_in[1];
  const float* embedw     = (const float*)d_in[2];
  const float* eps        = (const float*)d_in[3];
  const float* W1         = (const float*)d_in[4];
  const float* b1         = (const float*)d_in[5];
  const float* W2         = (const float*)d_in[6];
  const float* b2         = (const float*)d_in[7];
  const float* bn_g       = (const float*)d_in[8];
  const float* bn_b       = (const float*)d_in[9];
  const float* fc_W1      = (const float*)d_in[10];
  const float* fc_b1      = (const float*)d_in[11];
  const float* fc_bn_g    = (const float*)d_in[12];
  const float* fc_bn_b    = (const float*)d_in[13];
  const float* fc_W2      = (const float*)d_in[14];
  const float* fc_b2      = (const float*)d_in[15];

  // workspace: zcat [N,256] + agg [N,64] + stats + sort arrays  (~155 MB)
  float* zcat   = (float*)d_ws;                 // [N,256] layer outputs concat
  float* agg    = zcat + (long)NN * 256;        // [N,64]  (also h1 tmp / fc1 pre-BN)
  float* stats  = agg + (long)NN * D;           // [128]
  int*   csroff = (int*)(stats + 128);          // [NN+1]
  int*   bsum   = csroff + NN + 1;              // [512]
  int*   csrsrc = bsum + 512;                   // [NE]
  int*   rec    = csrsrc + NE;                  // [NE] packed records
  int*   S      = rec + NE;                     // [NP*392]
  // bf16 half-split mirror [2][N][32] overlays rec (dead after sort_kernel)
  bf16*  xh     = (bf16*)rec;                   // 12.8 MB = NE*4 B exactly

  const int rowBlocks  = NN / 4;                 // 25000
  const int gemmBlocks = (NN + 63) / 64;         // 1563
  const int aggBlocks  = NN / 16;                // 6250

  // ---- build CSR (by dst): private-region bucket sort, no global atomics ----
  bucket_kernel<<<NP, 256, 0, stream>>>(edge_index, rec, S);
  bucketsum_kernel<<<NB, 256, 0, stream>>>(S, bsum);
  scan2_kernel<<<1, 512, 0, stream>>>(bsum);
  sort_kernel<<<NB, 512, 0, stream>>>(rec, S, bsum, csroff, csrsrc);

  // ---- embedding -> zcat[:,0:64] + mirror ----
  embed_kernel<<<rowBlocks, 256, 0, stream>>>(node_deg, embedw, zcat, xh);

  for (int l = 0; l < 3; ++l) {
    // aggregation in two 32-dim halves (sequential dispatches: small L2 ws)
    agg_kernel<<<aggBlocks, 256, 0, stream>>>(csroff, csrsrc,
        (const unsigned*)xh, agg, 0);
    agg_kernel<<<aggBlocks, 256, 0, stream>>>(csroff, csrsrc,
        (const unsigned*)(xh + (long)NN * 32), agg, 1);
    // agg = leaky(((1+eps)z_l + agg) @ W1 + b1)   [in-place, row-local]
    gemm64_kernel<<<gemmBlocks, 256, 0, stream>>>(zcat + l * D, 256, 64,
        agg, eps, l, W1 + (long)l * D * D, b1 + (long)l * D, agg, 64, 1);
    // z_{l+1} = agg @ W2 + b2  (pre-BN)
    gemm64_kernel<<<gemmBlocks, 256, 0, stream>>>(agg, 64, 64,
        nullptr, nullptr, 0, W2 + (long)l * D * D, b2 + (long)l * D,
        zcat + (l + 1) * D, 256, 0);
    hipMemsetAsync(stats, 0, 128 * sizeof(float), stream);
    bn_stats_kernel<<<256, 256, 0, stream>>>(zcat + (l + 1) * D, 256, stats);
    bn_apply_kernel<<<rowBlocks, 256, 0, stream>>>(zcat + (l + 1) * D, 256, stats,
        bn_g + (long)l * D, bn_b + (long)l * D, zcat + (l + 1) * D, xh);
  }

  // ---- fc1: one K=256 GEMM over zcat -> agg (pre-BN) ----
  gemm64_kernel<<<gemmBlocks, 256, 0, stream>>>(zcat, 256, 256,
      nullptr, nullptr, 0, fc_W1, fc_b1, agg, 64, 0);
  hipMemsetAsync(stats, 0, 128 * sizeof(float), stream);
  bn_stats_kernel<<<256, 256, 0, stream>>>(agg, 64, stats);
  bn_apply_kernel<<<rowBlocks, 256, 0, stream>>>(agg, 64, stats,
      fc_bn_g, fc_bn_b, agg, nullptr);
  fc2_kernel<<<rowBlocks, 256, 0, stream>>>(agg, fc_W2, fc_b2, (float*)d_out);
}

// Round 10
// 717.758 us; speedup vs baseline: 1.2244x; 1.2244x over previous
//
#include <hip/hip_runtime.h>
#include <hip/hip_bf16.h>

#define NN 100000
#define NE 3200000
#define D 64
#define BN_EPS 1e-5f

#define NP 512       // producer blocks
#define CHUNK 6250   // edges per producer (512*6250 = 3.2M exactly)
#define NB 391       // dst buckets of 256 nodes (391*256 = 100096 >= NN)
#define SPREAD 16    // stats contention spread

typedef __hip_bfloat16 bf16;

__device__ __forceinline__ float2 bf2_to_f2(unsigned u) {
  union { unsigned ui; float f; } a, b;
  a.ui = u << 16;
  b.ui = u & 0xffff0000u;
  return make_float2(a.f, b.f);
}

// ---- embedding gather: zcat[:,0:64] = embed_deg[node_deg]; mirror to xh ----
__global__ __launch_bounds__(256) void embed_kernel(const int* __restrict__ deg,
    const float* __restrict__ emb, float* __restrict__ zcat,
    bf16* __restrict__ xh) {
  int idx = blockIdx.x * 256 + threadIdx.x;
  int i = idx >> 6, d = idx & 63;
  if (i < NN) {
    float v = emb[(long)deg[i] * D + d];
    zcat[(long)i * 256 + d] = v;
    xh[(long)(d >> 5) * NN * 32 + (long)i * 32 + (d & 31)] = __float2bfloat16(v);
  }
}

// ---- producer: bucket edges into private per-block regions ----
__global__ __launch_bounds__(256) void bucket_kernel(const int* __restrict__ ei,
    int* __restrict__ rec, int* __restrict__ S) {
  __shared__ int cntL[392];
  __shared__ int curL[392];
  __shared__ int scanbuf[256];
  int t = threadIdx.x;
  int p = blockIdx.x;
  int e0 = p * CHUNK;
  cntL[t] = 0;
  if (t < 136) cntL[256 + t] = 0;
  __syncthreads();
  for (int e = t; e < CHUNK; e += 256) {
    int dd = ei[NE + e0 + e];
    atomicAdd(&cntL[(unsigned)dd >> 8], 1);
  }
  __syncthreads();
  int a0 = 0, a1 = 0;
  if (t < 196) { a0 = cntL[2 * t]; a1 = cntL[2 * t + 1]; }
  int s = a0 + a1;
  scanbuf[t] = s;
  __syncthreads();
  for (int off = 1; off < 256; off <<= 1) {
    int x = (t >= off) ? scanbuf[t - off] : 0;
    __syncthreads();
    scanbuf[t] += x;
    __syncthreads();
  }
  int ex = scanbuf[t] - s;
  if (t < 196) {
    curL[2 * t]     = ex;
    curL[2 * t + 1] = ex + a0;
    S[p * 392 + 2 * t]     = e0 + ex;
    S[p * 392 + 2 * t + 1] = e0 + ex + a0;
  }
  __syncthreads();
  for (int e = t; e < CHUNK; e += 256) {
    int ss = ei[e0 + e];
    int dd = ei[NE + e0 + e];
    int b = (unsigned)dd >> 8;
    int pos = atomicAdd(&curL[b], 1);
    rec[e0 + pos] = ss | ((dd & 255) << 17);
  }
}

// ---- bucket totals ----
__global__ __launch_bounds__(256) void bucketsum_kernel(const int* __restrict__ S,
    int* __restrict__ bsum) {
  __shared__ int sh[256];
  int B = blockIdx.x;
  int t = threadIdx.x;
  int c = 0;
  for (int p = t; p < NP; p += 256)
    c += S[p * 392 + B + 1] - S[p * 392 + B];
  sh[t] = c;
  __syncthreads();
  for (int o = 128; o > 0; o >>= 1) {
    if (t < o) sh[t] += sh[t + o];
    __syncthreads();
  }
  if (t == 0) bsum[B] = sh[0];
}

// ---- exclusive scan of 391 bucket totals ----
__global__ __launch_bounds__(512) void scan2_kernel(int* __restrict__ bsum) {
  __shared__ int sh[512];
  int t = threadIdx.x;
  int v = (t < NB) ? bsum[t] : 0;
  sh[t] = v;
  __syncthreads();
  for (int o = 1; o < 512; o <<= 1) {
    int x = (t >= o) ? sh[t - o] : 0;
    __syncthreads();
    sh[t] += x;
    __syncthreads();
  }
  if (t < NB) bsum[t] = sh[t] - v;
}

// ---- sorter ----
__global__ __launch_bounds__(512) void sort_kernel(const int* __restrict__ rec,
    const int* __restrict__ S, const int* __restrict__ bsum,
    int* __restrict__ csroff, int* __restrict__ csrsrc) {
  __shared__ int cntL[256];
  __shared__ int curL[256];
  int t = threadIdx.x;
  int B = blockIdx.x;
  if (t < 256) cntL[t] = 0;
  __syncthreads();
  int lane = t & 15;
  int g = t >> 4;
  for (int p = g; p < NP; p += 32) {
    int s0 = S[p * 392 + B], s1 = S[p * 392 + B + 1];
    for (int e = s0 + lane; e < s1; e += 16)
      atomicAdd(&cntL[(unsigned)rec[e] >> 17], 1);
  }
  __syncthreads();
  int v = 0;
  if (t < 256) { v = cntL[t]; curL[t] = v; }
  __syncthreads();
  for (int o = 1; o < 256; o <<= 1) {
    int x = 0;
    if (t < 256 && t >= o) x = curL[t - o];
    __syncthreads();
    if (t < 256) curL[t] += x;
    __syncthreads();
  }
  int b0 = bsum[B];
  if (t < 256) {
    int excl = curL[t] - v;
    int node = B * 256 + t;
    if (node <= NN) csroff[node] = b0 + excl;
  }
  __syncthreads();
  if (t < 256) curL[t] = b0 + (curL[t] - v);
  __syncthreads();
  for (int p = g; p < NP; p += 32) {
    int s0 = S[p * 392 + B], s1 = S[p * 392 + B + 1];
    for (int e = s0 + lane; e < s1; e += 16) {
      int r = rec[e];
      int pos = atomicAdd(&curL[(unsigned)r >> 17], 1);
      csrsrc[pos] = r & 0x1FFFF;
    }
  }
}

// ---- aggregation, one 32-dim half per dispatch ----
__global__ __launch_bounds__(256) void agg_kernel(const int* __restrict__ off,
    const int* __restrict__ srcs, const unsigned* __restrict__ xh32,
    float* __restrict__ agg, int h) {
  int t = threadIdx.x;
  int lane = t & 15;
  int g = t >> 4;
  int i = blockIdx.x * 16 + g;
  int e0 = off[i], e1 = off[i + 1];
  float s0 = 0.0f, s1 = 0.0f;
  int e = e0;
  for (; e + 4 <= e1; e += 4) {
    int j0 = srcs[e + 0], j1 = srcs[e + 1], j2 = srcs[e + 2], j3 = srcs[e + 3];
    unsigned u0 = xh32[(long)j0 * 16 + lane];
    unsigned u1 = xh32[(long)j1 * 16 + lane];
    unsigned u2 = xh32[(long)j2 * 16 + lane];
    unsigned u3 = xh32[(long)j3 * 16 + lane];
    float2 f0 = bf2_to_f2(u0), f1 = bf2_to_f2(u1);
    float2 f2 = bf2_to_f2(u2), f3 = bf2_to_f2(u3);
    s0 += (f0.x + f1.x) + (f2.x + f3.x);
    s1 += (f0.y + f1.y) + (f2.y + f3.y);
  }
  for (; e < e1; e++) {
    float2 f = bf2_to_f2(xh32[(long)srcs[e] * 16 + lane]);
    s0 += f.x; s1 += f.y;
  }
  *(float2*)&agg[(long)i * D + h * 32 + 2 * lane] = make_float2(s0, s1);
}

// ---- fused layer: z = (leaky((a*x+agg)@W1+b1))@W2+b2, + BN partial stats ----
__global__ __launch_bounds__(256) void layer_kernel(
    const float* __restrict__ X,     // zcat slice l, stride 256
    const float* __restrict__ AGG,   // [N,64]
    const float* __restrict__ epsv, int l,
    const float* __restrict__ W1, const float* __restrict__ b1,
    const float* __restrict__ W2, const float* __restrict__ b2,
    float* __restrict__ Z,           // zcat slice l+1 (pre-BN), stride 256
    float* __restrict__ spread)      // [SPREAD][128]
{
  __shared__ float Ws[64][64];
  __shared__ float XsT[64][64];
  int t = threadIdx.x;
  int i0 = blockIdx.x * 64;
  float alpha = 1.0f + epsv[l];
  int c0 = (t & 15) * 4;
  int r0 = (t >> 4) * 4;
  int wr = t >> 4;
  int wc = (t & 15) * 4;

  // stage W1 + Xeff (transposed)
  #pragma unroll
  for (int j = 0; j < 4; j++)
    *(float4*)&Ws[wr + 16 * j][wc] = *(const float4*)&W1[(long)(wr + 16 * j) * D + wc];
  {
    int row = t & 63;
    int gi = i0 + row;
    int gis = (gi < NN) ? gi : NN - 1;
    int kb = (t >> 6) * 16;
    #pragma unroll
    for (int j = 0; j < 4; j++) {
      int k = kb + 4 * j;
      float4 xv = *(const float4*)&X[(long)gis * 256 + k];
      float4 a4 = *(const float4*)&AGG[(long)gis * D + k];
      xv.x = alpha * xv.x + a4.x;
      xv.y = alpha * xv.y + a4.y;
      xv.z = alpha * xv.z + a4.z;
      xv.w = alpha * xv.w + a4.w;
      XsT[k + 0][row] = xv.x;
      XsT[k + 1][row] = xv.y;
      XsT[k + 2][row] = xv.z;
      XsT[k + 3][row] = xv.w;
    }
  }
  __syncthreads();

  // gemm1 -> h (leaky)
  float4 h[4];
  {
    float4 b4 = *(const float4*)&b1[c0];
    #pragma unroll
    for (int r = 0; r < 4; r++) h[r] = b4;
  }
  #pragma unroll 8
  for (int k = 0; k < 64; k++) {
    float4 w4 = *(const float4*)&Ws[k][c0];
    float4 x4 = *(const float4*)&XsT[k][r0];
    h[0].x += x4.x * w4.x; h[0].y += x4.x * w4.y; h[0].z += x4.x * w4.z; h[0].w += x4.x * w4.w;
    h[1].x += x4.y * w4.x; h[1].y += x4.y * w4.y; h[1].z += x4.y * w4.z; h[1].w += x4.y * w4.w;
    h[2].x += x4.z * w4.x; h[2].y += x4.z * w4.y; h[2].z += x4.z * w4.z; h[2].w += x4.z * w4.w;
    h[3].x += x4.w * w4.x; h[3].y += x4.w * w4.y; h[3].z += x4.w * w4.z; h[3].w += x4.w * w4.w;
  }
  #pragma unroll
  for (int r = 0; r < 4; r++) {
    h[r].x = (h[r].x >= 0.0f) ? h[r].x : 0.01f * h[r].x;
    h[r].y = (h[r].y >= 0.0f) ? h[r].y : 0.01f * h[r].y;
    h[r].z = (h[r].z >= 0.0f) ? h[r].z : 0.01f * h[r].z;
    h[r].w = (h[r].w >= 0.0f) ? h[r].w : 0.01f * h[r].w;
  }
  __syncthreads();   // all reads of Ws/XsT done

  // h1^T into XsT (k = h1 col), W2 into Ws
  #pragma unroll
  for (int r = 0; r < 4; r++) {
    XsT[c0 + 0][r0 + r] = h[r].x;
    XsT[c0 + 1][r0 + r] = h[r].y;
    XsT[c0 + 2][r0 + r] = h[r].z;
    XsT[c0 + 3][r0 + r] = h[r].w;
  }
  #pragma unroll
  for (int j = 0; j < 4; j++)
    *(float4*)&Ws[wr + 16 * j][wc] = *(const float4*)&W2[(long)(wr + 16 * j) * D + wc];
  __syncthreads();

  // gemm2 -> z
  float4 z[4];
  {
    float4 b4 = *(const float4*)&b2[c0];
    #pragma unroll
    for (int r = 0; r < 4; r++) z[r] = b4;
  }
  #pragma unroll 8
  for (int k = 0; k < 64; k++) {
    float4 w4 = *(const float4*)&Ws[k][c0];
    float4 x4 = *(const float4*)&XsT[k][r0];
    z[0].x += x4.x * w4.x; z[0].y += x4.x * w4.y; z[0].z += x4.x * w4.z; z[0].w += x4.x * w4.w;
    z[1].x += x4.y * w4.x; z[1].y += x4.y * w4.y; z[1].z += x4.y * w4.z; z[1].w += x4.y * w4.w;
    z[2].x += x4.z * w4.x; z[2].y += x4.z * w4.y; z[2].z += x4.z * w4.z; z[2].w += x4.z * w4.w;
    z[3].x += x4.w * w4.x; z[3].y += x4.w * w4.y; z[3].z += x4.w * w4.z; z[3].w += x4.w * w4.w;
  }
  // store z (pre-BN)
  #pragma unroll
  for (int r = 0; r < 4; r++) {
    int gi = i0 + r0 + r;
    if (gi < NN) *(float4*)&Z[(long)gi * 256 + c0] = z[r];
  }

  // BN partial stats over this block's valid rows (reuse XsT as scratch)
  float s[4] = {0, 0, 0, 0}, sq[4] = {0, 0, 0, 0};
  #pragma unroll
  for (int r = 0; r < 4; r++) {
    if (i0 + r0 + r < NN) {
      s[0] += z[r].x; sq[0] += z[r].x * z[r].x;
      s[1] += z[r].y; sq[1] += z[r].y * z[r].y;
      s[2] += z[r].z; sq[2] += z[r].z * z[r].z;
      s[3] += z[r].w; sq[3] += z[r].w * z[r].w;
    }
  }
  __syncthreads();   // all reads of XsT done
  float* red = &XsT[0][0];   // [16][64] sums, then [16][64] sumsq at +1024
  int grp = t >> 4;
  #pragma unroll
  for (int j = 0; j < 4; j++) {
    red[grp * 64 + c0 + j] = s[j];
    red[1024 + grp * 64 + c0 + j] = sq[j];
  }
  __syncthreads();
  if (t < 64) {
    float a = 0.0f, b = 0.0f;
    #pragma unroll
    for (int g = 0; g < 16; g++) {
      a += red[g * 64 + t];
      b += red[1024 + g * 64 + t];
    }
    int slot = blockIdx.x & (SPREAD - 1);
    atomicAdd(&spread[slot * 128 + t], a);
    atomicAdd(&spread[slot * 128 + 64 + t], b);
  }
}

// ---- fc1: K=256 gemm + BN partial stats ----
__global__ __launch_bounds__(256) void fc1_kernel(
    const float* __restrict__ X,     // zcat, stride 256
    const float* __restrict__ W, const float* __restrict__ bias,
    float* __restrict__ Y,           // agg [N,64] pre-BN
    float* __restrict__ spread)
{
  __shared__ float Ws[64][64];
  __shared__ float XsT[64][64];
  int t = threadIdx.x;
  int i0 = blockIdx.x * 64;
  int c0 = (t & 15) * 4;
  int r0 = (t >> 4) * 4;
  int wr = t >> 4;
  int wc = (t & 15) * 4;

  float4 acc[4];
  {
    float4 b4 = *(const float4*)&bias[c0];
    #pragma unroll
    for (int r = 0; r < 4; r++) acc[r] = b4;
  }
  for (int kc = 0; kc < 256; kc += 64) {
    __syncthreads();
    #pragma unroll
    for (int j = 0; j < 4; j++)
      *(float4*)&Ws[wr + 16 * j][wc] = *(const float4*)&W[(long)(kc + wr + 16 * j) * D + wc];
    {
      int row = t & 63;
      int gi = i0 + row;
      int gis = (gi < NN) ? gi : NN - 1;
      int kb = (t >> 6) * 16;
      #pragma unroll
      for (int j = 0; j < 4; j++) {
        int k = kb + 4 * j;
        float4 xv = *(const float4*)&X[(long)gis * 256 + kc + k];
        XsT[k + 0][row] = xv.x;
        XsT[k + 1][row] = xv.y;
        XsT[k + 2][row] = xv.z;
        XsT[k + 3][row] = xv.w;
      }
    }
    __syncthreads();
    #pragma unroll 8
    for (int k = 0; k < 64; k++) {
      float4 w4 = *(const float4*)&Ws[k][c0];
      float4 x4 = *(const float4*)&XsT[k][r0];
      acc[0].x += x4.x * w4.x; acc[0].y += x4.x * w4.y; acc[0].z += x4.x * w4.z; acc[0].w += x4.x * w4.w;
      acc[1].x += x4.y * w4.x; acc[1].y += x4.y * w4.y; acc[1].z += x4.y * w4.z; acc[1].w += x4.y * w4.w;
      acc[2].x += x4.z * w4.x; acc[2].y += x4.z * w4.y; acc[2].z += x4.z * w4.z; acc[2].w += x4.z * w4.w;
      acc[3].x += x4.w * w4.x; acc[3].y += x4.w * w4.y; acc[3].z += x4.w * w4.z; acc[3].w += x4.w * w4.w;
    }
  }
  #pragma unroll
  for (int r = 0; r < 4; r++) {
    int gi = i0 + r0 + r;
    if (gi < NN) *(float4*)&Y[(long)gi * D + c0] = acc[r];
  }
  // BN partial stats
  float s[4] = {0, 0, 0, 0}, sq[4] = {0, 0, 0, 0};
  #pragma unroll
  for (int r = 0; r < 4; r++) {
    if (i0 + r0 + r < NN) {
      s[0] += acc[r].x; sq[0] += acc[r].x * acc[r].x;
      s[1] += acc[r].y; sq[1] += acc[r].y * acc[r].y;
      s[2] += acc[r].z; sq[2] += acc[r].z * acc[r].z;
      s[3] += acc[r].w; sq[3] += acc[r].w * acc[r].w;
    }
  }
  __syncthreads();
  float* red = &XsT[0][0];
  int grp = t >> 4;
  #pragma unroll
  for (int j = 0; j < 4; j++) {
    red[grp * 64 + c0 + j] = s[j];
    red[1024 + grp * 64 + c0 + j] = sq[j];
  }
  __syncthreads();
  if (t < 64) {
    float a = 0.0f, b = 0.0f;
    #pragma unroll
    for (int g = 0; g < 16; g++) {
      a += red[g * 64 + t];
      b += red[1024 + g * 64 + t];
    }
    int slot = blockIdx.x & (SPREAD - 1);
    atomicAdd(&spread[slot * 128 + t], a);
    atomicAdd(&spread[slot * 128 + 64 + t], b);
  }
}

// ---- reduce spread stats -> final [128] ----
__global__ __launch_bounds__(128) void bn_finalize_kernel(
    const float* __restrict__ spread, float* __restrict__ statsF) {
  int t = threadIdx.x;
  float a = 0.0f;
  #pragma unroll
  for (int g = 0; g < SPREAD; g++) a += spread[g * 128 + t];
  statsF[t] = a;
}

// ---- BN apply + leaky (zcat slice in place, + bf16 half-split mirror) ----
__global__ __launch_bounds__(256) void bn_apply_kernel(float* __restrict__ Zs,
    const float* __restrict__ stats,
    const float* __restrict__ g, const float* __restrict__ b,
    bf16* __restrict__ Outh) {
  int idx = blockIdx.x * 256 + threadIdx.x;
  int i = idx >> 6, d = idx & 63;
  if (i >= NN) return;
  float invn = 1.0f / (float)NN;
  float mu = stats[d] * invn;
  float var = fmaxf(stats[64 + d] * invn - mu * mu, 0.0f);
  float sc = g[d] * rsqrtf(var + BN_EPS);
  float v = sc * (Zs[(long)i * 256 + d] - mu) + b[d];
  v = (v >= 0.0f) ? v : 0.01f * v;
  Zs[(long)i * 256 + d] = v;
  Outh[(long)(d >> 5) * NN * 32 + (long)i * 32 + (d & 31)] = __float2bfloat16(v);
}

// ---- fused fc BN-apply + fc2 dot + sigmoid ----
__global__ __launch_bounds__(256) void fc2bn_kernel(const float* __restrict__ H,
    const float* __restrict__ stats,
    const float* __restrict__ g, const float* __restrict__ b,
    const float* __restrict__ W2, const float* __restrict__ b2,
    float* __restrict__ out) {
  int tid = threadIdx.x;
  int k = tid & 63, q = tid >> 6;
  int i = blockIdx.x * 4 + q;
  float invn = 1.0f / (float)NN;
  float mu = stats[k] * invn;
  float var = fmaxf(stats[64 + k] * invn - mu * mu, 0.0f);
  float sc = g[k] * rsqrtf(var + BN_EPS);
  float v = 0.0f;
  if (i < NN) {
    float hv = sc * (H[(long)i * D + k] - mu) + b[k];
    hv = (hv >= 0.0f) ? hv : 0.01f * hv;
    v = hv * W2[k];
  }
  #pragma unroll
  for (int off = 32; off > 0; off >>= 1)
    v += __shfl_down(v, off);
  if (k == 0 && i < NN) {
    float x = v + b2[0];
    out[i] = 1.0f / (1.0f + __expf(-x));
  }
}

extern "C" void kernel_launch(void* const* d_in, const int* in_sizes, int n_in,
                              void* d_out, int out_size, void* d_ws, size_t ws_size,
                              hipStream_t stream) {
  const int*   node_deg   = (const int*)d_in[0];
  const int*   edge_index = (const int*)d_in[1];
  const float* embedw     = (const float*)d_in[2];
  const float* eps        = (const float*)d_in[3];
  const float* W1         = (const float*)d_in[4];
  const float* b1         = (const float*)d_in[5];
  const float* W2         = (const float*)d_in[6];
  const float* b2         = (const float*)d_in[7];
  const float* bn_g       = (const float*)d_in[8];
  const float* bn_b       = (const float*)d_in[9];
  const float* fc_W1      = (const float*)d_in[10];
  const float* fc_b1      = (const float*)d_in[11];
  const float* fc_bn_g    = (const float*)d_in[12];
  const float* fc_bn_b    = (const float*)d_in[13];
  const float* fc_W2      = (const float*)d_in[14];
  const float* fc_b2      = (const float*)d_in[15];

  float* zcat   = (float*)d_ws;                 // [N,256]
  float* agg    = zcat + (long)NN * 256;        // [N,64]
  float* statsS = agg + (long)NN * D;           // 4 * SPREAD*128 = 8192
  float* statsF = statsS + 4 * SPREAD * 128;    // 4 * 128 = 512
  int*   csroff = (int*)(statsF + 512);         // [NN+1]
  int*   bsum   = csroff + NN + 1;              // [512]
  int*   csrsrc = bsum + 512;                   // [NE]
  int*   rec    = csrsrc + NE;                  // [NE]
  int*   S      = rec + NE;                     // [NP*392]
  bf16*  xh     = (bf16*)rec;                   // [2][N][32] overlays rec

  const int rowBlocks  = NN / 4;                 // 25000
  const int gemmBlocks = (NN + 63) / 64;         // 1563
  const int aggBlocks  = NN / 16;                // 6250

  // ---- CSR build ----
  bucket_kernel<<<NP, 256, 0, stream>>>(edge_index, rec, S);
  bucketsum_kernel<<<NB, 256, 0, stream>>>(S, bsum);
  scan2_kernel<<<1, 512, 0, stream>>>(bsum);
  sort_kernel<<<NB, 512, 0, stream>>>(rec, S, bsum, csroff, csrsrc);

  // zero all spread-stats once
  hipMemsetAsync(statsS, 0, (size_t)(4 * SPREAD * 128 + 512) * sizeof(float), stream);

  // ---- embedding ----
  embed_kernel<<<rowBlocks, 256, 0, stream>>>(node_deg, embedw, zcat, xh);

  for (int l = 0; l < 3; ++l) {
    agg_kernel<<<aggBlocks, 256, 0, stream>>>(csroff, csrsrc,
        (const unsigned*)xh, agg, 0);
    agg_kernel<<<aggBlocks, 256, 0, stream>>>(csroff, csrsrc,
        (const unsigned*)(xh + (long)NN * 32), agg, 1);
    layer_kernel<<<gemmBlocks, 256, 0, stream>>>(zcat + l * D, agg, eps, l,
        W1 + (long)l * D * D, b1 + (long)l * D,
        W2 + (long)l * D * D, b2 + (long)l * D,
        zcat + (l + 1) * D, statsS + (long)l * SPREAD * 128);
    bn_finalize_kernel<<<1, 128, 0, stream>>>(statsS + (long)l * SPREAD * 128,
        statsF + (long)l * 128);
    bn_apply_kernel<<<rowBlocks, 256, 0, stream>>>(zcat + (l + 1) * D,
        statsF + (long)l * 128, bn_g + (long)l * D, bn_b + (long)l * D, xh);
  }

  // ---- fc1 (+stats), finalize, fused BN+fc2 ----
  fc1_kernel<<<gemmBlocks, 256, 0, stream>>>(zcat, fc_W1, fc_b1, agg,
      statsS + 3L * SPREAD * 128);
  bn_finalize_kernel<<<1, 128, 0, stream>>>(statsS + 3L * SPREAD * 128,
      statsF + 3L * 128);
  fc2bn_kernel<<<rowBlocks, 256, 0, stream>>>(agg, statsF + 3L * 128,
      fc_bn_g, fc_bn_b, fc_W2, fc_b2, (float*)d_out);
}

// Round 11
// 697.056 us; speedup vs baseline: 1.2608x; 1.0297x over previous
//
#include <hip/hip_runtime.h>
#include <hip/hip_bf16.h>

#define NN 100000
#define NE 3200000
#define D 64
#define BN_EPS 1e-5f

#define NP 512       // producer blocks
#define CHUNK 6250   // edges per producer (512*6250 = 3.2M exactly)
#define NB 391       // dst buckets of 256 nodes (391*256 = 100096 >= NN)
#define SPREAD 16    // stats contention spread

typedef __hip_bfloat16 bf16;

__device__ __forceinline__ float2 bf2_to_f2(unsigned u) {
  union { unsigned ui; float f; } a, b;
  a.ui = u << 16;
  b.ui = u & 0xffff0000u;
  return make_float2(a.f, b.f);
}

// xh mirror layout: [4][N][16] bf16 — slice s holds dims [16s,16s+16)
// ---- embedding gather: zcat[:,0:64] = embed_deg[node_deg]; mirror to xh ----
__global__ __launch_bounds__(256) void embed_kernel(const int* __restrict__ deg,
    const float* __restrict__ emb, float* __restrict__ zcat,
    bf16* __restrict__ xh) {
  int idx = blockIdx.x * 256 + threadIdx.x;
  int i = idx >> 6, d = idx & 63;
  if (i < NN) {
    float v = emb[(long)deg[i] * D + d];
    zcat[(long)i * 256 + d] = v;
    xh[(long)(d >> 4) * NN * 16 + (long)i * 16 + (d & 15)] = __float2bfloat16(v);
  }
}

// ---- producer: bucket edges into private per-block regions ----
__global__ __launch_bounds__(256) void bucket_kernel(const int* __restrict__ ei,
    int* __restrict__ rec, int* __restrict__ S) {
  __shared__ int cntL[392];
  __shared__ int curL[392];
  __shared__ int scanbuf[256];
  int t = threadIdx.x;
  int p = blockIdx.x;
  int e0 = p * CHUNK;
  cntL[t] = 0;
  if (t < 136) cntL[256 + t] = 0;
  __syncthreads();
  for (int e = t; e < CHUNK; e += 256) {
    int dd = ei[NE + e0 + e];
    atomicAdd(&cntL[(unsigned)dd >> 8], 1);
  }
  __syncthreads();
  int a0 = 0, a1 = 0;
  if (t < 196) { a0 = cntL[2 * t]; a1 = cntL[2 * t + 1]; }
  int s = a0 + a1;
  scanbuf[t] = s;
  __syncthreads();
  for (int off = 1; off < 256; off <<= 1) {
    int x = (t >= off) ? scanbuf[t - off] : 0;
    __syncthreads();
    scanbuf[t] += x;
    __syncthreads();
  }
  int ex = scanbuf[t] - s;
  if (t < 196) {
    curL[2 * t]     = ex;
    curL[2 * t + 1] = ex + a0;
    S[p * 392 + 2 * t]     = e0 + ex;
    S[p * 392 + 2 * t + 1] = e0 + ex + a0;
  }
  __syncthreads();
  for (int e = t; e < CHUNK; e += 256) {
    int ss = ei[e0 + e];
    int dd = ei[NE + e0 + e];
    int b = (unsigned)dd >> 8;
    int pos = atomicAdd(&curL[b], 1);
    rec[e0 + pos] = ss | ((dd & 255) << 17);
  }
}

// ---- bucket totals ----
__global__ __launch_bounds__(256) void bucketsum_kernel(const int* __restrict__ S,
    int* __restrict__ bsum) {
  __shared__ int sh[256];
  int B = blockIdx.x;
  int t = threadIdx.x;
  int c = 0;
  for (int p = t; p < NP; p += 256)
    c += S[p * 392 + B + 1] - S[p * 392 + B];
  sh[t] = c;
  __syncthreads();
  for (int o = 128; o > 0; o >>= 1) {
    if (t < o) sh[t] += sh[t + o];
    __syncthreads();
  }
  if (t == 0) bsum[B] = sh[0];
}

// ---- exclusive scan of 391 bucket totals ----
__global__ __launch_bounds__(512) void scan2_kernel(int* __restrict__ bsum) {
  __shared__ int sh[512];
  int t = threadIdx.x;
  int v = (t < NB) ? bsum[t] : 0;
  sh[t] = v;
  __syncthreads();
  for (int o = 1; o < 512; o <<= 1) {
    int x = (t >= o) ? sh[t - o] : 0;
    __syncthreads();
    sh[t] += x;
    __syncthreads();
  }
  if (t < NB) bsum[t] = sh[t] - v;
}

// ---- sorter ----
__global__ __launch_bounds__(512) void sort_kernel(const int* __restrict__ rec,
    const int* __restrict__ S, const int* __restrict__ bsum,
    int* __restrict__ csroff, int* __restrict__ csrsrc) {
  __shared__ int cntL[256];
  __shared__ int curL[256];
  int t = threadIdx.x;
  int B = blockIdx.x;
  if (t < 256) cntL[t] = 0;
  __syncthreads();
  int lane = t & 15;
  int g = t >> 4;
  for (int p = g; p < NP; p += 32) {
    int s0 = S[p * 392 + B], s1 = S[p * 392 + B + 1];
    for (int e = s0 + lane; e < s1; e += 16)
      atomicAdd(&cntL[(unsigned)rec[e] >> 17], 1);
  }
  __syncthreads();
  int v = 0;
  if (t < 256) { v = cntL[t]; curL[t] = v; }
  __syncthreads();
  for (int o = 1; o < 256; o <<= 1) {
    int x = 0;
    if (t < 256 && t >= o) x = curL[t - o];
    __syncthreads();
    if (t < 256) curL[t] += x;
    __syncthreads();
  }
  int b0 = bsum[B];
  if (t < 256) {
    int excl = curL[t] - v;
    int node = B * 256 + t;
    if (node <= NN) csroff[node] = b0 + excl;
  }
  __syncthreads();
  if (t < 256) curL[t] = b0 + (curL[t] - v);
  __syncthreads();
  for (int p = g; p < NP; p += 32) {
    int s0 = S[p * 392 + B], s1 = S[p * 392 + B + 1];
    for (int e = s0 + lane; e < s1; e += 16) {
      int r = rec[e];
      int pos = atomicAdd(&curL[(unsigned)r >> 17], 1);
      csrsrc[pos] = r & 0x1FFFF;
    }
  }
}

// ---- aggregation: XCD-pinned 16-dim slices. slice = blockIdx & 3 so each
//      XCD (blockIdx%8) always touches one 3.2 MB slice -> fits 4 MB L2. ----
__global__ __launch_bounds__(256) void agg_kernel(const int* __restrict__ off,
    const int* __restrict__ srcs, const unsigned* __restrict__ xh32,
    float* __restrict__ agg) {
  int t = threadIdx.x;
  int lane = t & 7;               // 8 lanes x 2 dims = 16 dims
  int g = t >> 3;                 // 32 node-groups per block
  int b = blockIdx.x;
  int slice = b & 3;
  int i = (b >> 2) * 32 + g;      // 3125 chunks * 32 = 100000 exact
  const unsigned* base = xh32 + (long)slice * NN * 8;
  int e0 = off[i], e1 = off[i + 1];
  float s0 = 0.0f, s1 = 0.0f;
  int e = e0;
  for (; e + 4 <= e1; e += 4) {
    int j0 = srcs[e + 0], j1 = srcs[e + 1], j2 = srcs[e + 2], j3 = srcs[e + 3];
    unsigned u0 = base[(long)j0 * 8 + lane];
    unsigned u1 = base[(long)j1 * 8 + lane];
    unsigned u2 = base[(long)j2 * 8 + lane];
    unsigned u3 = base[(long)j3 * 8 + lane];
    float2 f0 = bf2_to_f2(u0), f1 = bf2_to_f2(u1);
    float2 f2 = bf2_to_f2(u2), f3 = bf2_to_f2(u3);
    s0 += (f0.x + f1.x) + (f2.x + f3.x);
    s1 += (f0.y + f1.y) + (f2.y + f3.y);
  }
  for (; e < e1; e++) {
    float2 f = bf2_to_f2(base[(long)srcs[e] * 8 + lane]);
    s0 += f.x; s1 += f.y;
  }
  *(float2*)&agg[(long)i * D + slice * 16 + 2 * lane] = make_float2(s0, s1);
}

// ---- fused layer: z = (leaky((a*x+agg)@W1+b1))@W2+b2, + BN partial stats ----
__global__ __launch_bounds__(256) void layer_kernel(
    const float* __restrict__ X,     // zcat slice l, stride 256
    const float* __restrict__ AGG,   // [N,64]
    const float* __restrict__ epsv, int l,
    const float* __restrict__ W1, const float* __restrict__ b1,
    const float* __restrict__ W2, const float* __restrict__ b2,
    float* __restrict__ Z,           // zcat slice l+1 (pre-BN), stride 256
    float* __restrict__ spread)      // [SPREAD][128]
{
  __shared__ float Ws[64][64];
  __shared__ float XsT[64][64];
  int t = threadIdx.x;
  int i0 = blockIdx.x * 64;
  float alpha = 1.0f + epsv[l];
  int c0 = (t & 15) * 4;
  int r0 = (t >> 4) * 4;
  int wr = t >> 4;
  int wc = (t & 15) * 4;

  #pragma unroll
  for (int j = 0; j < 4; j++)
    *(float4*)&Ws[wr + 16 * j][wc] = *(const float4*)&W1[(long)(wr + 16 * j) * D + wc];
  {
    int row = t & 63;
    int gi = i0 + row;
    int gis = (gi < NN) ? gi : NN - 1;
    int kb = (t >> 6) * 16;
    #pragma unroll
    for (int j = 0; j < 4; j++) {
      int k = kb + 4 * j;
      float4 xv = *(const float4*)&X[(long)gis * 256 + k];
      float4 a4 = *(const float4*)&AGG[(long)gis * D + k];
      xv.x = alpha * xv.x + a4.x;
      xv.y = alpha * xv.y + a4.y;
      xv.z = alpha * xv.z + a4.z;
      xv.w = alpha * xv.w + a4.w;
      XsT[k + 0][row] = xv.x;
      XsT[k + 1][row] = xv.y;
      XsT[k + 2][row] = xv.z;
      XsT[k + 3][row] = xv.w;
    }
  }
  __syncthreads();

  float4 h[4];
  {
    float4 b4 = *(const float4*)&b1[c0];
    #pragma unroll
    for (int r = 0; r < 4; r++) h[r] = b4;
  }
  #pragma unroll 8
  for (int k = 0; k < 64; k++) {
    float4 w4 = *(const float4*)&Ws[k][c0];
    float4 x4 = *(const float4*)&XsT[k][r0];
    h[0].x += x4.x * w4.x; h[0].y += x4.x * w4.y; h[0].z += x4.x * w4.z; h[0].w += x4.x * w4.w;
    h[1].x += x4.y * w4.x; h[1].y += x4.y * w4.y; h[1].z += x4.y * w4.z; h[1].w += x4.y * w4.w;
    h[2].x += x4.z * w4.x; h[2].y += x4.z * w4.y; h[2].z += x4.z * w4.z; h[2].w += x4.z * w4.w;
    h[3].x += x4.w * w4.x; h[3].y += x4.w * w4.y; h[3].z += x4.w * w4.z; h[3].w += x4.w * w4.w;
  }
  #pragma unroll
  for (int r = 0; r < 4; r++) {
    h[r].x = (h[r].x >= 0.0f) ? h[r].x : 0.01f * h[r].x;
    h[r].y = (h[r].y >= 0.0f) ? h[r].y : 0.01f * h[r].y;
    h[r].z = (h[r].z >= 0.0f) ? h[r].z : 0.01f * h[r].z;
    h[r].w = (h[r].w >= 0.0f) ? h[r].w : 0.01f * h[r].w;
  }
  __syncthreads();

  #pragma unroll
  for (int r = 0; r < 4; r++) {
    XsT[c0 + 0][r0 + r] = h[r].x;
    XsT[c0 + 1][r0 + r] = h[r].y;
    XsT[c0 + 2][r0 + r] = h[r].z;
    XsT[c0 + 3][r0 + r] = h[r].w;
  }
  #pragma unroll
  for (int j = 0; j < 4; j++)
    *(float4*)&Ws[wr + 16 * j][wc] = *(const float4*)&W2[(long)(wr + 16 * j) * D + wc];
  __syncthreads();

  float4 z[4];
  {
    float4 b4 = *(const float4*)&b2[c0];
    #pragma unroll
    for (int r = 0; r < 4; r++) z[r] = b4;
  }
  #pragma unroll 8
  for (int k = 0; k < 64; k++) {
    float4 w4 = *(const float4*)&Ws[k][c0];
    float4 x4 = *(const float4*)&XsT[k][r0];
    z[0].x += x4.x * w4.x; z[0].y += x4.x * w4.y; z[0].z += x4.x * w4.z; z[0].w += x4.x * w4.w;
    z[1].x += x4.y * w4.x; z[1].y += x4.y * w4.y; z[1].z += x4.y * w4.z; z[1].w += x4.y * w4.w;
    z[2].x += x4.z * w4.x; z[2].y += x4.z * w4.y; z[2].z += x4.z * w4.z; z[2].w += x4.z * w4.w;
    z[3].x += x4.w * w4.x; z[3].y += x4.w * w4.y; z[3].z += x4.w * w4.z; z[3].w += x4.w * w4.w;
  }
  #pragma unroll
  for (int r = 0; r < 4; r++) {
    int gi = i0 + r0 + r;
    if (gi < NN) *(float4*)&Z[(long)gi * 256 + c0] = z[r];
  }

  float s[4] = {0, 0, 0, 0}, sq[4] = {0, 0, 0, 0};
  #pragma unroll
  for (int r = 0; r < 4; r++) {
    if (i0 + r0 + r < NN) {
      s[0] += z[r].x; sq[0] += z[r].x * z[r].x;
      s[1] += z[r].y; sq[1] += z[r].y * z[r].y;
      s[2] += z[r].z; sq[2] += z[r].z * z[r].z;
      s[3] += z[r].w; sq[3] += z[r].w * z[r].w;
    }
  }
  __syncthreads();
  float* red = &XsT[0][0];
  int grp = t >> 4;
  #pragma unroll
  for (int j = 0; j < 4; j++) {
    red[grp * 64 + c0 + j] = s[j];
    red[1024 + grp * 64 + c0 + j] = sq[j];
  }
  __syncthreads();
  if (t < 64) {
    float a = 0.0f, b = 0.0f;
    #pragma unroll
    for (int g = 0; g < 16; g++) {
      a += red[g * 64 + t];
      b += red[1024 + g * 64 + t];
    }
    int slot = blockIdx.x & (SPREAD - 1);
    atomicAdd(&spread[slot * 128 + t], a);
    atomicAdd(&spread[slot * 128 + 64 + t], b);
  }
}

// ---- fc1: K=256 gemm + BN partial stats ----
__global__ __launch_bounds__(256) void fc1_kernel(
    const float* __restrict__ X,
    const float* __restrict__ W, const float* __restrict__ bias,
    float* __restrict__ Y, float* __restrict__ spread)
{
  __shared__ float Ws[64][64];
  __shared__ float XsT[64][64];
  int t = threadIdx.x;
  int i0 = blockIdx.x * 64;
  int c0 = (t & 15) * 4;
  int r0 = (t >> 4) * 4;
  int wr = t >> 4;
  int wc = (t & 15) * 4;

  float4 acc[4];
  {
    float4 b4 = *(const float4*)&bias[c0];
    #pragma unroll
    for (int r = 0; r < 4; r++) acc[r] = b4;
  }
  for (int kc = 0; kc < 256; kc += 64) {
    __syncthreads();
    #pragma unroll
    for (int j = 0; j < 4; j++)
      *(float4*)&Ws[wr + 16 * j][wc] = *(const float4*)&W[(long)(kc + wr + 16 * j) * D + wc];
    {
      int row = t & 63;
      int gi = i0 + row;
      int gis = (gi < NN) ? gi : NN - 1;
      int kb = (t >> 6) * 16;
      #pragma unroll
      for (int j = 0; j < 4; j++) {
        int k = kb + 4 * j;
        float4 xv = *(const float4*)&X[(long)gis * 256 + kc + k];
        XsT[k + 0][row] = xv.x;
        XsT[k + 1][row] = xv.y;
        XsT[k + 2][row] = xv.z;
        XsT[k + 3][row] = xv.w;
      }
    }
    __syncthreads();
    #pragma unroll 8
    for (int k = 0; k < 64; k++) {
      float4 w4 = *(const float4*)&Ws[k][c0];
      float4 x4 = *(const float4*)&XsT[k][r0];
      acc[0].x += x4.x * w4.x; acc[0].y += x4.x * w4.y; acc[0].z += x4.x * w4.z; acc[0].w += x4.x * w4.w;
      acc[1].x += x4.y * w4.x; acc[1].y += x4.y * w4.y; acc[1].z += x4.y * w4.z; acc[1].w += x4.y * w4.w;
      acc[2].x += x4.z * w4.x; acc[2].y += x4.z * w4.y; acc[2].z += x4.z * w4.z; acc[2].w += x4.z * w4.w;
      acc[3].x += x4.w * w4.x; acc[3].y += x4.w * w4.y; acc[3].z += x4.w * w4.z; acc[3].w += x4.w * w4.w;
    }
  }
  #pragma unroll
  for (int r = 0; r < 4; r++) {
    int gi = i0 + r0 + r;
    if (gi < NN) *(float4*)&Y[(long)gi * D + c0] = acc[r];
  }
  float s[4] = {0, 0, 0, 0}, sq[4] = {0, 0, 0, 0};
  #pragma unroll
  for (int r = 0; r < 4; r++) {
    if (i0 + r0 + r < NN) {
      s[0] += acc[r].x; sq[0] += acc[r].x * acc[r].x;
      s[1] += acc[r].y; sq[1] += acc[r].y * acc[r].y;
      s[2] += acc[r].z; sq[2] += acc[r].z * acc[r].z;
      s[3] += acc[r].w; sq[3] += acc[r].w * acc[r].w;
    }
  }
  __syncthreads();
  float* red = &XsT[0][0];
  int grp = t >> 4;
  #pragma unroll
  for (int j = 0; j < 4; j++) {
    red[grp * 64 + c0 + j] = s[j];
    red[1024 + grp * 64 + c0 + j] = sq[j];
  }
  __syncthreads();
  if (t < 64) {
    float a = 0.0f, b = 0.0f;
    #pragma unroll
    for (int g = 0; g < 16; g++) {
      a += red[g * 64 + t];
      b += red[1024 + g * 64 + t];
    }
    int slot = blockIdx.x & (SPREAD - 1);
    atomicAdd(&spread[slot * 128 + t], a);
    atomicAdd(&spread[slot * 128 + 64 + t], b);
  }
}

// ---- reduce spread stats -> final [128] ----
__global__ __launch_bounds__(128) void bn_finalize_kernel(
    const float* __restrict__ spread, float* __restrict__ statsF) {
  int t = threadIdx.x;
  float a = 0.0f;
  #pragma unroll
  for (int g = 0; g < SPREAD; g++) a += spread[g * 128 + t];
  statsF[t] = a;
}

// ---- BN apply + leaky (zcat slice in place, + bf16 sliced mirror) ----
__global__ __launch_bounds__(256) void bn_apply_kernel(float* __restrict__ Zs,
    const float* __restrict__ stats,
    const float* __restrict__ g, const float* __restrict__ b,
    bf16* __restrict__ Outh) {
  int idx = blockIdx.x * 256 + threadIdx.x;
  int i = idx >> 6, d = idx & 63;
  if (i >= NN) return;
  float invn = 1.0f / (float)NN;
  float mu = stats[d] * invn;
  float var = fmaxf(stats[64 + d] * invn - mu * mu, 0.0f);
  float sc = g[d] * rsqrtf(var + BN_EPS);
  float v = sc * (Zs[(long)i * 256 + d] - mu) + b[d];
  v = (v >= 0.0f) ? v : 0.01f * v;
  Zs[(long)i * 256 + d] = v;
  Outh[(long)(d >> 4) * NN * 16 + (long)i * 16 + (d & 15)] = __float2bfloat16(v);
}

// ---- fused fc BN-apply + fc2 dot + sigmoid ----
__global__ __launch_bounds__(256) void fc2bn_kernel(const float* __restrict__ H,
    const float* __restrict__ stats,
    const float* __restrict__ g, const float* __restrict__ b,
    const float* __restrict__ W2, const float* __restrict__ b2,
    float* __restrict__ out) {
  int tid = threadIdx.x;
  int k = tid & 63, q = tid >> 6;
  int i = blockIdx.x * 4 + q;
  float invn = 1.0f / (float)NN;
  float mu = stats[k] * invn;
  float var = fmaxf(stats[64 + k] * invn - mu * mu, 0.0f);
  float sc = g[k] * rsqrtf(var + BN_EPS);
  float v = 0.0f;
  if (i < NN) {
    float hv = sc * (H[(long)i * D + k] - mu) + b[k];
    hv = (hv >= 0.0f) ? hv : 0.01f * hv;
    v = hv * W2[k];
  }
  #pragma unroll
  for (int off = 32; off > 0; off >>= 1)
    v += __shfl_down(v, off);
  if (k == 0 && i < NN) {
    float x = v + b2[0];
    out[i] = 1.0f / (1.0f + __expf(-x));
  }
}

extern "C" void kernel_launch(void* const* d_in, const int* in_sizes, int n_in,
                              void* d_out, int out_size, void* d_ws, size_t ws_size,
                              hipStream_t stream) {
  const int*   node_deg   = (const int*)d_in[0];
  const int*   edge_index = (const int*)d_in[1];
  const float* embedw     = (const float*)d_in[2];
  const float* eps        = (const float*)d_in[3];
  const float* W1         = (const float*)d_in[4];
  const float* b1         = (const float*)d_in[5];
  const float* W2         = (const float*)d_in[6];
  const float* b2         = (const float*)d_in[7];
  const float* bn_g       = (const float*)d_in[8];
  const float* bn_b       = (const float*)d_in[9];
  const float* fc_W1      = (const float*)d_in[10];
  const float* fc_b1      = (const float*)d_in[11];
  const float* fc_bn_g    = (const float*)d_in[12];
  const float* fc_bn_b    = (const float*)d_in[13];
  const float* fc_W2      = (const float*)d_in[14];
  const float* fc_b2      = (const float*)d_in[15];

  float* zcat   = (float*)d_ws;                 // [N,256]
  float* agg    = zcat + (long)NN * 256;        // [N,64]
  float* statsS = agg + (long)NN * D;           // 4 * SPREAD*128
  float* statsF = statsS + 4 * SPREAD * 128;    // 4 * 128
  int*   csroff = (int*)(statsF + 512);         // [NN+1]
  int*   bsum   = csroff + NN + 1;              // [512]
  int*   csrsrc = bsum + 512;                   // [NE]
  int*   rec    = csrsrc + NE;                  // [NE]
  int*   S      = rec + NE;                     // [NP*392]
  bf16*  xh     = (bf16*)rec;                   // [4][N][16] overlays rec (12.8 MB)

  const int rowBlocks  = NN / 4;                 // 25000
  const int gemmBlocks = (NN + 63) / 64;         // 1563
  const int aggBlocks  = (NN / 32) * 4;          // 3125 chunks x 4 slices = 12500

  // ---- CSR build ----
  bucket_kernel<<<NP, 256, 0, stream>>>(edge_index, rec, S);
  bucketsum_kernel<<<NB, 256, 0, stream>>>(S, bsum);
  scan2_kernel<<<1, 512, 0, stream>>>(bsum);
  sort_kernel<<<NB, 512, 0, stream>>>(rec, S, bsum, csroff, csrsrc);

  hipMemsetAsync(statsS, 0, (size_t)(4 * SPREAD * 128 + 512) * sizeof(float), stream);

  embed_kernel<<<rowBlocks, 256, 0, stream>>>(node_deg, embedw, zcat, xh);

  for (int l = 0; l < 3; ++l) {
    agg_kernel<<<aggBlocks, 256, 0, stream>>>(csroff, csrsrc,
        (const unsigned*)xh, agg);
    layer_kernel<<<gemmBlocks, 256, 0, stream>>>(zcat + l * D, agg, eps, l,
        W1 + (long)l * D * D, b1 + (long)l * D,
        W2 + (long)l * D * D, b2 + (long)l * D,
        zcat + (l + 1) * D, statsS + (long)l * SPREAD * 128);
    bn_finalize_kernel<<<1, 128, 0, stream>>>(statsS + (long)l * SPREAD * 128,
        statsF + (long)l * 128);
    bn_apply_kernel<<<rowBlocks, 256, 0, stream>>>(zcat + (l + 1) * D,
        statsF + (long)l * 128, bn_g + (long)l * D, bn_b + (long)l * D, xh);
  }

  fc1_kernel<<<gemmBlocks, 256, 0, stream>>>(zcat, fc_W1, fc_b1, agg,
      statsS + 3L * SPREAD * 128);
  bn_finalize_kernel<<<1, 128, 0, stream>>>(statsS + 3L * SPREAD * 128,
      statsF + 3L * 128);
  fc2bn_kernel<<<rowBlocks, 256, 0, stream>>>(agg, statsF + 3L * 128,
      fc_bn_g, fc_bn_b, fc_W2, fc_b2, (float*)d_out);
}

// Round 12
// 623.838 us; speedup vs baseline: 1.4088x; 1.1174x over previous
//
#include <hip/hip_runtime.h>
#include <hip/hip_bf16.h>

#define NN 100000
#define NE 3200000
#define D 64
#define BN_EPS 1e-5f

#define NP 512       // producer blocks
#define CHUNK 6250   // edges per producer (512*6250 = 3.2M exactly)
#define NB 391       // dst buckets of 256 nodes (391*256 = 100096 >= NN)
#define SPREAD 16    // stats contention spread

typedef __hip_bfloat16 bf16;

__device__ __forceinline__ float2 bf2_to_f2(unsigned u) {
  union { unsigned ui; float f; } a, b;
  a.ui = u << 16;
  b.ui = u & 0xffff0000u;
  return make_float2(a.f, b.f);
}

// ---- embedding gather: zcat[:,0:64] = embed_deg[node_deg] ----
__global__ __launch_bounds__(256) void embed_kernel(const int* __restrict__ deg,
    const float* __restrict__ emb, float* __restrict__ zcat) {
  int idx = blockIdx.x * 256 + threadIdx.x;
  int i = idx >> 6, d = idx & 63;
  if (i < NN) zcat[(long)i * 256 + d] = emb[(long)deg[i] * D + d];
}

// ---- producer: bucket edges into private per-block regions ----
__global__ __launch_bounds__(256) void bucket_kernel(const int* __restrict__ ei,
    int* __restrict__ rec, int* __restrict__ S) {
  __shared__ int cntL[392];
  __shared__ int curL[392];
  __shared__ int scanbuf[256];
  int t = threadIdx.x;
  int p = blockIdx.x;
  int e0 = p * CHUNK;
  cntL[t] = 0;
  if (t < 136) cntL[256 + t] = 0;
  __syncthreads();
  for (int e = t; e < CHUNK; e += 256) {
    int dd = ei[NE + e0 + e];
    atomicAdd(&cntL[(unsigned)dd >> 8], 1);
  }
  __syncthreads();
  int a0 = 0, a1 = 0;
  if (t < 196) { a0 = cntL[2 * t]; a1 = cntL[2 * t + 1]; }
  int s = a0 + a1;
  scanbuf[t] = s;
  __syncthreads();
  for (int off = 1; off < 256; off <<= 1) {
    int x = (t >= off) ? scanbuf[t - off] : 0;
    __syncthreads();
    scanbuf[t] += x;
    __syncthreads();
  }
  int ex = scanbuf[t] - s;
  if (t < 196) {
    curL[2 * t]     = ex;
    curL[2 * t + 1] = ex + a0;
    S[p * 392 + 2 * t]     = e0 + ex;
    S[p * 392 + 2 * t + 1] = e0 + ex + a0;
  }
  __syncthreads();
  for (int e = t; e < CHUNK; e += 256) {
    int ss = ei[e0 + e];
    int dd = ei[NE + e0 + e];
    int b = (unsigned)dd >> 8;
    int pos = atomicAdd(&curL[b], 1);
    rec[e0 + pos] = ss | ((dd & 255) << 17);
  }
}

// ---- bucket totals ----
__global__ __launch_bounds__(256) void bucketsum_kernel(const int* __restrict__ S,
    int* __restrict__ bsum) {
  __shared__ int sh[256];
  int B = blockIdx.x;
  int t = threadIdx.x;
  int c = 0;
  for (int p = t; p < NP; p += 256)
    c += S[p * 392 + B + 1] - S[p * 392 + B];
  sh[t] = c;
  __syncthreads();
  for (int o = 128; o > 0; o >>= 1) {
    if (t < o) sh[t] += sh[t + o];
    __syncthreads();
  }
  if (t == 0) bsum[B] = sh[0];
}

// ---- exclusive scan of 391 bucket totals ----
__global__ __launch_bounds__(512) void scan2_kernel(int* __restrict__ bsum) {
  __shared__ int sh[512];
  int t = threadIdx.x;
  int v = (t < NB) ? bsum[t] : 0;
  sh[t] = v;
  __syncthreads();
  for (int o = 1; o < 512; o <<= 1) {
    int x = (t >= o) ? sh[t - o] : 0;
    __syncthreads();
    sh[t] += x;
    __syncthreads();
  }
  if (t < NB) bsum[t] = sh[t] - v;
}

// ---- sorter + fused neighbor-degree histogram (cnt8 for layer-0 agg GEMM) ----
__global__ __launch_bounds__(512) void sort_kernel(const int* __restrict__ rec,
    const int* __restrict__ S, const int* __restrict__ bsum,
    const int* __restrict__ deg,
    int* __restrict__ csroff, int* __restrict__ csrsrc,
    unsigned* __restrict__ cnt8) {
  __shared__ int cntL[256];
  __shared__ int curL[256];
  __shared__ unsigned hist[256 * 65];   // [dstLocal][degree], padded stride 65
  int t = threadIdx.x;
  int B = blockIdx.x;
  if (t < 256) cntL[t] = 0;
  for (int k = t; k < 256 * 65; k += 512) hist[k] = 0;
  __syncthreads();
  int lane = t & 15;
  int g = t >> 4;
  // pass 1: per-node histogram + neighbor-degree histogram
  for (int p = g; p < NP; p += 32) {
    int s0 = S[p * 392 + B], s1 = S[p * 392 + B + 1];
    for (int e = s0 + lane; e < s1; e += 16) {
      int r = rec[e];
      int dl = (unsigned)r >> 17;
      atomicAdd(&cntL[dl], 1);
      atomicAdd(&hist[dl * 65 + deg[r & 0x1FFFF]], 1u);
    }
  }
  __syncthreads();
  // exclusive scan of 256 counters
  int v = 0;
  if (t < 256) { v = cntL[t]; curL[t] = v; }
  __syncthreads();
  for (int o = 1; o < 256; o <<= 1) {
    int x = 0;
    if (t < 256 && t >= o) x = curL[t - o];
    __syncthreads();
    if (t < 256) curL[t] += x;
    __syncthreads();
  }
  int b0 = bsum[B];
  if (t < 256) {
    int excl = curL[t] - v;
    int node = B * 256 + t;
    if (node <= NN) csroff[node] = b0 + excl;
  }
  __syncthreads();
  if (t < 256) curL[t] = b0 + (curL[t] - v);
  // write cnt8: node t's 64 byte-counts packed into 16 u32 (one 64B line/thread)
  if (t < 256) {
    int node = B * 256 + t;
    if (node < NN) {
      #pragma unroll
      for (int j = 0; j < 16; j++) {
        unsigned p = (hist[t * 65 + 4 * j] & 255)
                   | ((hist[t * 65 + 4 * j + 1] & 255) << 8)
                   | ((hist[t * 65 + 4 * j + 2] & 255) << 16)
                   | ((hist[t * 65 + 4 * j + 3] & 255) << 24);
        cnt8[(long)node * 16 + j] = p;
      }
    }
  }
  __syncthreads();
  // pass 2: scatter records into block-owned csr range
  for (int p = g; p < NP; p += 32) {
    int s0 = S[p * 392 + B], s1 = S[p * 392 + B + 1];
    for (int e = s0 + lane; e < s1; e += 16) {
      int r = rec[e];
      int pos = atomicAdd(&curL[(unsigned)r >> 17], 1);
      csrsrc[pos] = r & 0x1FFFF;
    }
  }
}

// ---- layer-0 aggregation as dense GEMM: agg = cnt8 @ embed  ----
__global__ __launch_bounds__(256) void agg0_kernel(const unsigned* __restrict__ cnt8,
    const float* __restrict__ emb, float* __restrict__ agg) {
  __shared__ float Es[64][64];     // embed[c][d]
  __shared__ float XsT[64][64];    // counts as float, [c][row]
  int t = threadIdx.x;
  int i0 = blockIdx.x * 64;
  int wr = t >> 4, wc = (t & 15) * 4;
  #pragma unroll
  for (int j = 0; j < 4; j++)
    *(float4*)&Es[wr + 16 * j][wc] = *(const float4*)&emb[(long)(wr + 16 * j) * D + wc];
  {
    int row = t & 63;
    int gi = i0 + row;
    int gis = (gi < NN) ? gi : NN - 1;
    int jb = (t >> 6) * 4;
    #pragma unroll
    for (int j = 0; j < 4; j++) {
      unsigned u = cnt8[(long)gis * 16 + jb + j];
      int k = (jb + j) * 4;
      XsT[k + 0][row] = (float)(u & 255);
      XsT[k + 1][row] = (float)((u >> 8) & 255);
      XsT[k + 2][row] = (float)((u >> 16) & 255);
      XsT[k + 3][row] = (float)(u >> 24);
    }
  }
  int c0 = (t & 15) * 4;
  int r0 = (t >> 4) * 4;
  float4 acc[4];
  #pragma unroll
  for (int r = 0; r < 4; r++) acc[r] = make_float4(0.f, 0.f, 0.f, 0.f);
  __syncthreads();
  #pragma unroll 8
  for (int k = 0; k < 64; k++) {
    float4 w4 = *(const float4*)&Es[k][c0];
    float4 x4 = *(const float4*)&XsT[k][r0];
    acc[0].x += x4.x * w4.x; acc[0].y += x4.x * w4.y; acc[0].z += x4.x * w4.z; acc[0].w += x4.x * w4.w;
    acc[1].x += x4.y * w4.x; acc[1].y += x4.y * w4.y; acc[1].z += x4.y * w4.z; acc[1].w += x4.y * w4.w;
    acc[2].x += x4.z * w4.x; acc[2].y += x4.z * w4.y; acc[2].z += x4.z * w4.z; acc[2].w += x4.z * w4.w;
    acc[3].x += x4.w * w4.x; acc[3].y += x4.w * w4.y; acc[3].z += x4.w * w4.z; acc[3].w += x4.w * w4.w;
  }
  #pragma unroll
  for (int r = 0; r < 4; r++) {
    int gi = i0 + r0 + r;
    if (gi < NN) *(float4*)&agg[(long)gi * D + c0] = acc[r];
  }
}

// ---- aggregation (layers 1,2): XCD-pinned 16-dim slices ----
__global__ __launch_bounds__(256) void agg_kernel(const int* __restrict__ off,
    const int* __restrict__ srcs, const unsigned* __restrict__ xh32,
    float* __restrict__ agg) {
  int t = threadIdx.x;
  int lane = t & 7;
  int g = t >> 3;
  int b = blockIdx.x;
  int slice = b & 3;
  int i = (b >> 2) * 32 + g;
  const unsigned* base = xh32 + (long)slice * NN * 8;
  int e0 = off[i], e1 = off[i + 1];
  float s0 = 0.0f, s1 = 0.0f;
  int e = e0;
  for (; e + 4 <= e1; e += 4) {
    int j0 = srcs[e + 0], j1 = srcs[e + 1], j2 = srcs[e + 2], j3 = srcs[e + 3];
    unsigned u0 = base[(long)j0 * 8 + lane];
    unsigned u1 = base[(long)j1 * 8 + lane];
    unsigned u2 = base[(long)j2 * 8 + lane];
    unsigned u3 = base[(long)j3 * 8 + lane];
    float2 f0 = bf2_to_f2(u0), f1 = bf2_to_f2(u1);
    float2 f2 = bf2_to_f2(u2), f3 = bf2_to_f2(u3);
    s0 += (f0.x + f1.x) + (f2.x + f3.x);
    s1 += (f0.y + f1.y) + (f2.y + f3.y);
  }
  for (; e < e1; e++) {
    float2 f = bf2_to_f2(base[(long)srcs[e] * 8 + lane]);
    s0 += f.x; s1 += f.y;
  }
  *(float2*)&agg[(long)i * D + slice * 16 + 2 * lane] = make_float2(s0, s1);
}

// ---- fused layer: z = (leaky((a*x+agg)@W1+b1))@W2+b2, + BN partial stats ----
__global__ __launch_bounds__(256) void layer_kernel(
    const float* __restrict__ X,
    const float* __restrict__ AGG,
    const float* __restrict__ epsv, int l,
    const float* __restrict__ W1, const float* __restrict__ b1,
    const float* __restrict__ W2, const float* __restrict__ b2,
    float* __restrict__ Z, float* __restrict__ spread)
{
  __shared__ float Ws[64][64];
  __shared__ float XsT[64][64];
  int t = threadIdx.x;
  int i0 = blockIdx.x * 64;
  float alpha = 1.0f + epsv[l];
  int c0 = (t & 15) * 4;
  int r0 = (t >> 4) * 4;
  int wr = t >> 4;
  int wc = (t & 15) * 4;

  #pragma unroll
  for (int j = 0; j < 4; j++)
    *(float4*)&Ws[wr + 16 * j][wc] = *(const float4*)&W1[(long)(wr + 16 * j) * D + wc];
  {
    int row = t & 63;
    int gi = i0 + row;
    int gis = (gi < NN) ? gi : NN - 1;
    int kb = (t >> 6) * 16;
    #pragma unroll
    for (int j = 0; j < 4; j++) {
      int k = kb + 4 * j;
      float4 xv = *(const float4*)&X[(long)gis * 256 + k];
      float4 a4 = *(const float4*)&AGG[(long)gis * D + k];
      xv.x = alpha * xv.x + a4.x;
      xv.y = alpha * xv.y + a4.y;
      xv.z = alpha * xv.z + a4.z;
      xv.w = alpha * xv.w + a4.w;
      XsT[k + 0][row] = xv.x;
      XsT[k + 1][row] = xv.y;
      XsT[k + 2][row] = xv.z;
      XsT[k + 3][row] = xv.w;
    }
  }
  __syncthreads();

  float4 h[4];
  {
    float4 b4 = *(const float4*)&b1[c0];
    #pragma unroll
    for (int r = 0; r < 4; r++) h[r] = b4;
  }
  #pragma unroll 8
  for (int k = 0; k < 64; k++) {
    float4 w4 = *(const float4*)&Ws[k][c0];
    float4 x4 = *(const float4*)&XsT[k][r0];
    h[0].x += x4.x * w4.x; h[0].y += x4.x * w4.y; h[0].z += x4.x * w4.z; h[0].w += x4.x * w4.w;
    h[1].x += x4.y * w4.x; h[1].y += x4.y * w4.y; h[1].z += x4.y * w4.z; h[1].w += x4.y * w4.w;
    h[2].x += x4.z * w4.x; h[2].y += x4.z * w4.y; h[2].z += x4.z * w4.z; h[2].w += x4.z * w4.w;
    h[3].x += x4.w * w4.x; h[3].y += x4.w * w4.y; h[3].z += x4.w * w4.z; h[3].w += x4.w * w4.w;
  }
  #pragma unroll
  for (int r = 0; r < 4; r++) {
    h[r].x = (h[r].x >= 0.0f) ? h[r].x : 0.01f * h[r].x;
    h[r].y = (h[r].y >= 0.0f) ? h[r].y : 0.01f * h[r].y;
    h[r].z = (h[r].z >= 0.0f) ? h[r].z : 0.01f * h[r].z;
    h[r].w = (h[r].w >= 0.0f) ? h[r].w : 0.01f * h[r].w;
  }
  __syncthreads();

  #pragma unroll
  for (int r = 0; r < 4; r++) {
    XsT[c0 + 0][r0 + r] = h[r].x;
    XsT[c0 + 1][r0 + r] = h[r].y;
    XsT[c0 + 2][r0 + r] = h[r].z;
    XsT[c0 + 3][r0 + r] = h[r].w;
  }
  #pragma unroll
  for (int j = 0; j < 4; j++)
    *(float4*)&Ws[wr + 16 * j][wc] = *(const float4*)&W2[(long)(wr + 16 * j) * D + wc];
  __syncthreads();

  float4 z[4];
  {
    float4 b4 = *(const float4*)&b2[c0];
    #pragma unroll
    for (int r = 0; r < 4; r++) z[r] = b4;
  }
  #pragma unroll 8
  for (int k = 0; k < 64; k++) {
    float4 w4 = *(const float4*)&Ws[k][c0];
    float4 x4 = *(const float4*)&XsT[k][r0];
    z[0].x += x4.x * w4.x; z[0].y += x4.x * w4.y; z[0].z += x4.x * w4.z; z[0].w += x4.x * w4.w;
    z[1].x += x4.y * w4.x; z[1].y += x4.y * w4.y; z[1].z += x4.y * w4.z; z[1].w += x4.y * w4.w;
    z[2].x += x4.z * w4.x; z[2].y += x4.z * w4.y; z[2].z += x4.z * w4.z; z[2].w += x4.z * w4.w;
    z[3].x += x4.w * w4.x; z[3].y += x4.w * w4.y; z[3].z += x4.w * w4.z; z[3].w += x4.w * w4.w;
  }
  #pragma unroll
  for (int r = 0; r < 4; r++) {
    int gi = i0 + r0 + r;
    if (gi < NN) *(float4*)&Z[(long)gi * 256 + c0] = z[r];
  }

  float s[4] = {0, 0, 0, 0}, sq[4] = {0, 0, 0, 0};
  #pragma unroll
  for (int r = 0; r < 4; r++) {
    if (i0 + r0 + r < NN) {
      s[0] += z[r].x; sq[0] += z[r].x * z[r].x;
      s[1] += z[r].y; sq[1] += z[r].y * z[r].y;
      s[2] += z[r].z; sq[2] += z[r].z * z[r].z;
      s[3] += z[r].w; sq[3] += z[r].w * z[r].w;
    }
  }
  __syncthreads();
  float* red = &XsT[0][0];
  int grp = t >> 4;
  #pragma unroll
  for (int j = 0; j < 4; j++) {
    red[grp * 64 + c0 + j] = s[j];
    red[1024 + grp * 64 + c0 + j] = sq[j];
  }
  __syncthreads();
  if (t < 64) {
    float a = 0.0f, b = 0.0f;
    #pragma unroll
    for (int g = 0; g < 16; g++) {
      a += red[g * 64 + t];
      b += red[1024 + g * 64 + t];
    }
    int slot = blockIdx.x & (SPREAD - 1);
    atomicAdd(&spread[slot * 128 + t], a);
    atomicAdd(&spread[slot * 128 + 64 + t], b);
  }
}

// ---- fc1: K=256 gemm + BN partial stats ----
__global__ __launch_bounds__(256) void fc1_kernel(
    const float* __restrict__ X,
    const float* __restrict__ W, const float* __restrict__ bias,
    float* __restrict__ Y, float* __restrict__ spread)
{
  __shared__ float Ws[64][64];
  __shared__ float XsT[64][64];
  int t = threadIdx.x;
  int i0 = blockIdx.x * 64;
  int c0 = (t & 15) * 4;
  int r0 = (t >> 4) * 4;
  int wr = t >> 4;
  int wc = (t & 15) * 4;

  float4 acc[4];
  {
    float4 b4 = *(const float4*)&bias[c0];
    #pragma unroll
    for (int r = 0; r < 4; r++) acc[r] = b4;
  }
  for (int kc = 0; kc < 256; kc += 64) {
    __syncthreads();
    #pragma unroll
    for (int j = 0; j < 4; j++)
      *(float4*)&Ws[wr + 16 * j][wc] = *(const float4*)&W[(long)(kc + wr + 16 * j) * D + wc];
    {
      int row = t & 63;
      int gi = i0 + row;
      int gis = (gi < NN) ? gi : NN - 1;
      int kb = (t >> 6) * 16;
      #pragma unroll
      for (int j = 0; j < 4; j++) {
        int k = kb + 4 * j;
        float4 xv = *(const float4*)&X[(long)gis * 256 + kc + k];
        XsT[k + 0][row] = xv.x;
        XsT[k + 1][row] = xv.y;
        XsT[k + 2][row] = xv.z;
        XsT[k + 3][row] = xv.w;
      }
    }
    __syncthreads();
    #pragma unroll 8
    for (int k = 0; k < 64; k++) {
      float4 w4 = *(const float4*)&Ws[k][c0];
      float4 x4 = *(const float4*)&XsT[k][r0];
      acc[0].x += x4.x * w4.x; acc[0].y += x4.x * w4.y; acc[0].z += x4.x * w4.z; acc[0].w += x4.x * w4.w;
      acc[1].x += x4.y * w4.x; acc[1].y += x4.y * w4.y; acc[1].z += x4.y * w4.z; acc[1].w += x4.y * w4.w;
      acc[2].x += x4.z * w4.x; acc[2].y += x4.z * w4.y; acc[2].z += x4.z * w4.z; acc[2].w += x4.z * w4.w;
      acc[3].x += x4.w * w4.x; acc[3].y += x4.w * w4.y; acc[3].z += x4.w * w4.z; acc[3].w += x4.w * w4.w;
    }
  }
  #pragma unroll
  for (int r = 0; r < 4; r++) {
    int gi = i0 + r0 + r;
    if (gi < NN) *(float4*)&Y[(long)gi * D + c0] = acc[r];
  }
  float s[4] = {0, 0, 0, 0}, sq[4] = {0, 0, 0, 0};
  #pragma unroll
  for (int r = 0; r < 4; r++) {
    if (i0 + r0 + r < NN) {
      s[0] += acc[r].x; sq[0] += acc[r].x * acc[r].x;
      s[1] += acc[r].y; sq[1] += acc[r].y * acc[r].y;
      s[2] += acc[r].z; sq[2] += acc[r].z * acc[r].z;
      s[3] += acc[r].w; sq[3] += acc[r].w * acc[r].w;
    }
  }
  __syncthreads();
  float* red = &XsT[0][0];
  int grp = t >> 4;
  #pragma unroll
  for (int j = 0; j < 4; j++) {
    red[grp * 64 + c0 + j] = s[j];
    red[1024 + grp * 64 + c0 + j] = sq[j];
  }
  __syncthreads();
  if (t < 64) {
    float a = 0.0f, b = 0.0f;
    #pragma unroll
    for (int g = 0; g < 16; g++) {
      a += red[g * 64 + t];
      b += red[1024 + g * 64 + t];
    }
    int slot = blockIdx.x & (SPREAD - 1);
    atomicAdd(&spread[slot * 128 + t], a);
    atomicAdd(&spread[slot * 128 + 64 + t], b);
  }
}

// ---- reduce spread stats -> final [128] ----
__global__ __launch_bounds__(128) void bn_finalize_kernel(
    const float* __restrict__ spread, float* __restrict__ statsF) {
  int t = threadIdx.x;
  float a = 0.0f;
  #pragma unroll
  for (int g = 0; g < SPREAD; g++) a += spread[g * 128 + t];
  statsF[t] = a;
}

// ---- BN apply + leaky (zcat slice in place, + bf16 sliced mirror) ----
__global__ __launch_bounds__(256) void bn_apply_kernel(float* __restrict__ Zs,
    const float* __restrict__ stats,
    const float* __restrict__ g, const float* __restrict__ b,
    bf16* __restrict__ Outh) {
  int idx = blockIdx.x * 256 + threadIdx.x;
  int i = idx >> 6, d = idx & 63;
  if (i >= NN) return;
  float invn = 1.0f / (float)NN;
  float mu = stats[d] * invn;
  float var = fmaxf(stats[64 + d] * invn - mu * mu, 0.0f);
  float sc = g[d] * rsqrtf(var + BN_EPS);
  float v = sc * (Zs[(long)i * 256 + d] - mu) + b[d];
  v = (v >= 0.0f) ? v : 0.01f * v;
  Zs[(long)i * 256 + d] = v;
  Outh[(long)(d >> 4) * NN * 16 + (long)i * 16 + (d & 15)] = __float2bfloat16(v);
}

// ---- fused fc BN-apply + fc2 dot + sigmoid ----
__global__ __launch_bounds__(256) void fc2bn_kernel(const float* __restrict__ H,
    const float* __restrict__ stats,
    const float* __restrict__ g, const float* __restrict__ b,
    const float* __restrict__ W2, const float* __restrict__ b2,
    float* __restrict__ out) {
  int tid = threadIdx.x;
  int k = tid & 63, q = tid >> 6;
  int i = blockIdx.x * 4 + q;
  float invn = 1.0f / (float)NN;
  float mu = stats[k] * invn;
  float var = fmaxf(stats[64 + k] * invn - mu * mu, 0.0f);
  float sc = g[k] * rsqrtf(var + BN_EPS);
  float v = 0.0f;
  if (i < NN) {
    float hv = sc * (H[(long)i * D + k] - mu) + b[k];
    hv = (hv >= 0.0f) ? hv : 0.01f * hv;
    v = hv * W2[k];
  }
  #pragma unroll
  for (int off = 32; off > 0; off >>= 1)
    v += __shfl_down(v, off);
  if (k == 0 && i < NN) {
    float x = v + b2[0];
    out[i] = 1.0f / (1.0f + __expf(-x));
  }
}

extern "C" void kernel_launch(void* const* d_in, const int* in_sizes, int n_in,
                              void* d_out, int out_size, void* d_ws, size_t ws_size,
                              hipStream_t stream) {
  const int*   node_deg   = (const int*)d_in[0];
  const int*   edge_index = (const int*)d_in[1];
  const float* embedw     = (const float*)d_in[2];
  const float* eps        = (const float*)d_in[3];
  const float* W1         = (const float*)d_in[4];
  const float* b1         = (const float*)d_in[5];
  const float* W2         = (const float*)d_in[6];
  const float* b2         = (const float*)d_in[7];
  const float* bn_g       = (const float*)d_in[8];
  const float* bn_b       = (const float*)d_in[9];
  const float* fc_W1      = (const float*)d_in[10];
  const float* fc_b1      = (const float*)d_in[11];
  const float* fc_bn_g    = (const float*)d_in[12];
  const float* fc_bn_b    = (const float*)d_in[13];
  const float* fc_W2      = (const float*)d_in[14];
  const float* fc_b2      = (const float*)d_in[15];

  float* zcat   = (float*)d_ws;                 // [N,256]
  float* agg    = zcat + (long)NN * 256;        // [N,64]
  float* statsS = agg + (long)NN * D;           // 4 * SPREAD*128
  float* statsF = statsS + 4 * SPREAD * 128;    // 4 * 128
  int*   csroff = (int*)(statsF + 512);         // [NN+1]
  int*   bsum   = csroff + NN + 1;              // [512]
  int*   csrsrc = bsum + 512;                   // [NE]
  int*   rec    = csrsrc + NE;                  // [NE]
  int*   S      = rec + NE;                     // [NP*392]
  unsigned* cnt8 = (unsigned*)(S + NP * 392);   // [N,16] u32 (byte counts)
  bf16*  xh     = (bf16*)rec;                   // [4][N][16] overlays rec (12.8 MB)

  const int rowBlocks  = NN / 4;                 // 25000
  const int gemmBlocks = (NN + 63) / 64;         // 1563
  const int aggBlocks  = (NN / 32) * 4;          // 12500

  // ---- CSR build + neighbor-degree histogram ----
  bucket_kernel<<<NP, 256, 0, stream>>>(edge_index, rec, S);
  bucketsum_kernel<<<NB, 256, 0, stream>>>(S, bsum);
  scan2_kernel<<<1, 512, 0, stream>>>(bsum);
  sort_kernel<<<NB, 512, 0, stream>>>(rec, S, bsum, node_deg,
      csroff, csrsrc, cnt8);

  hipMemsetAsync(statsS, 0, (size_t)(4 * SPREAD * 128 + 512) * sizeof(float), stream);

  embed_kernel<<<rowBlocks, 256, 0, stream>>>(node_deg, embedw, zcat);

  for (int l = 0; l < 3; ++l) {
    if (l == 0)
      agg0_kernel<<<gemmBlocks, 256, 0, stream>>>(cnt8, embedw, agg);
    else
      agg_kernel<<<aggBlocks, 256, 0, stream>>>(csroff, csrsrc,
          (const unsigned*)xh, agg);
    layer_kernel<<<gemmBlocks, 256, 0, stream>>>(zcat + l * D, agg, eps, l,
        W1 + (long)l * D * D, b1 + (long)l * D,
        W2 + (long)l * D * D, b2 + (long)l * D,
        zcat + (l + 1) * D, statsS + (long)l * SPREAD * 128);
    bn_finalize_kernel<<<1, 128, 0, stream>>>(statsS + (long)l * SPREAD * 128,
        statsF + (long)l * 128);
    bn_apply_kernel<<<rowBlocks, 256, 0, stream>>>(zcat + (l + 1) * D,
        statsF + (long)l * 128, bn_g + (long)l * D, bn_b + (long)l * D, xh);
  }

  fc1_kernel<<<gemmBlocks, 256, 0, stream>>>(zcat, fc_W1, fc_b1, agg,
      statsS + 3L * SPREAD * 128);
  bn_finalize_kernel<<<1, 128, 0, stream>>>(statsS + 3L * SPREAD * 128,
      statsF + 3L * 128);
  fc2bn_kernel<<<rowBlocks, 256, 0, stream>>>(agg, statsF + 3L * 128,
      fc_bn_g, fc_bn_b, fc_W2, fc_b2, (float*)d_out);
}

// Round 13
// 536.722 us; speedup vs baseline: 1.6374x; 1.1623x over previous
//
#include <hip/hip_runtime.h>
#include <hip/hip_bf16.h>

#define NN 100000
#define NE 3200000
#define D 64
#define BN_EPS 1e-5f

#define NP 512       // producer blocks
#define CHUNK 6250   // edges per producer (512*6250 = 3.2M exactly)
#define NB 391       // dst buckets of 256 nodes (391*256 = 100096 >= NN)
#define SPREAD 16    // stats contention spread

typedef float v2f __attribute__((ext_vector_type(2)));

// ---- embedding gather: zcat[:,0:64] = embed_deg[node_deg] ----
__global__ __launch_bounds__(256) void embed_kernel(const int* __restrict__ deg,
    const float* __restrict__ emb, float* __restrict__ zcat) {
  int idx = blockIdx.x * 256 + threadIdx.x;
  int i = idx >> 6, d = idx & 63;
  if (i < NN) zcat[(long)i * 256 + d] = emb[(long)deg[i] * D + d];
}

// ---- producer: bucket edges into private per-block regions ----
__global__ __launch_bounds__(256) void bucket_kernel(const int* __restrict__ ei,
    int* __restrict__ rec, int* __restrict__ S) {
  __shared__ int cntL[392];
  __shared__ int curL[392];
  __shared__ int scanbuf[256];
  int t = threadIdx.x;
  int p = blockIdx.x;
  int e0 = p * CHUNK;
  cntL[t] = 0;
  if (t < 136) cntL[256 + t] = 0;
  __syncthreads();
  for (int e = t; e < CHUNK; e += 256) {
    int dd = ei[NE + e0 + e];
    atomicAdd(&cntL[(unsigned)dd >> 8], 1);
  }
  __syncthreads();
  int a0 = 0, a1 = 0;
  if (t < 196) { a0 = cntL[2 * t]; a1 = cntL[2 * t + 1]; }
  int s = a0 + a1;
  scanbuf[t] = s;
  __syncthreads();
  for (int off = 1; off < 256; off <<= 1) {
    int x = (t >= off) ? scanbuf[t - off] : 0;
    __syncthreads();
    scanbuf[t] += x;
    __syncthreads();
  }
  int ex = scanbuf[t] - s;
  if (t < 196) {
    curL[2 * t]     = ex;
    curL[2 * t + 1] = ex + a0;
    S[p * 392 + 2 * t]     = e0 + ex;
    S[p * 392 + 2 * t + 1] = e0 + ex + a0;
  }
  __syncthreads();
  for (int e = t; e < CHUNK; e += 256) {
    int ss = ei[e0 + e];
    int dd = ei[NE + e0 + e];
    int b = (unsigned)dd >> 8;
    int pos = atomicAdd(&curL[b], 1);
    rec[e0 + pos] = ss | ((dd & 255) << 17);
  }
}

// ---- bucket totals ----
__global__ __launch_bounds__(256) void bucketsum_kernel(const int* __restrict__ S,
    int* __restrict__ bsum) {
  __shared__ int sh[256];
  int B = blockIdx.x;
  int t = threadIdx.x;
  int c = 0;
  for (int p = t; p < NP; p += 256)
    c += S[p * 392 + B + 1] - S[p * 392 + B];
  sh[t] = c;
  __syncthreads();
  for (int o = 128; o > 0; o >>= 1) {
    if (t < o) sh[t] += sh[t + o];
    __syncthreads();
  }
  if (t == 0) bsum[B] = sh[0];
}

// ---- exclusive scan of 391 bucket totals ----
__global__ __launch_bounds__(512) void scan2_kernel(int* __restrict__ bsum) {
  __shared__ int sh[512];
  int t = threadIdx.x;
  int v = (t < NB) ? bsum[t] : 0;
  sh[t] = v;
  __syncthreads();
  for (int o = 1; o < 512; o <<= 1) {
    int x = (t >= o) ? sh[t - o] : 0;
    __syncthreads();
    sh[t] += x;
    __syncthreads();
  }
  if (t < NB) bsum[t] = sh[t] - v;
}

// ---- sorter + fused neighbor-degree histogram (cnt8 for layer-0 agg GEMM) ----
__global__ __launch_bounds__(512) void sort_kernel(const int* __restrict__ rec,
    const int* __restrict__ S, const int* __restrict__ bsum,
    const int* __restrict__ deg,
    int* __restrict__ csroff, int* __restrict__ csrsrc,
    unsigned* __restrict__ cnt8) {
  __shared__ int cntL[256];
  __shared__ int curL[256];
  __shared__ unsigned hist[256 * 65];
  int t = threadIdx.x;
  int B = blockIdx.x;
  if (t < 256) cntL[t] = 0;
  for (int k = t; k < 256 * 65; k += 512) hist[k] = 0;
  __syncthreads();
  int lane = t & 15;
  int g = t >> 4;
  for (int p = g; p < NP; p += 32) {
    int s0 = S[p * 392 + B], s1 = S[p * 392 + B + 1];
    for (int e = s0 + lane; e < s1; e += 16) {
      int r = rec[e];
      int dl = (unsigned)r >> 17;
      atomicAdd(&cntL[dl], 1);
      atomicAdd(&hist[dl * 65 + deg[r & 0x1FFFF]], 1u);
    }
  }
  __syncthreads();
  int v = 0;
  if (t < 256) { v = cntL[t]; curL[t] = v; }
  __syncthreads();
  for (int o = 1; o < 256; o <<= 1) {
    int x = 0;
    if (t < 256 && t >= o) x = curL[t - o];
    __syncthreads();
    if (t < 256) curL[t] += x;
    __syncthreads();
  }
  int b0 = bsum[B];
  if (t < 256) {
    int excl = curL[t] - v;
    int node = B * 256 + t;
    if (node <= NN) csroff[node] = b0 + excl;
  }
  __syncthreads();
  if (t < 256) curL[t] = b0 + (curL[t] - v);
  if (t < 256) {
    int node = B * 256 + t;
    if (node < NN) {
      #pragma unroll
      for (int j = 0; j < 16; j++) {
        unsigned p = (hist[t * 65 + 4 * j] & 255)
                   | ((hist[t * 65 + 4 * j + 1] & 255) << 8)
                   | ((hist[t * 65 + 4 * j + 2] & 255) << 16)
                   | ((hist[t * 65 + 4 * j + 3] & 255) << 24);
        cnt8[(long)node * 16 + j] = p;
      }
    }
  }
  __syncthreads();
  for (int p = g; p < NP; p += 32) {
    int s0 = S[p * 392 + B], s1 = S[p * 392 + B + 1];
    for (int e = s0 + lane; e < s1; e += 16) {
      int r = rec[e];
      int pos = atomicAdd(&curL[(unsigned)r >> 17], 1);
      csrsrc[pos] = r & 0x1FFFF;
    }
  }
}

// ---- layer-0 aggregation as dense GEMM: agg = cnt8 @ embed ----
__global__ __launch_bounds__(256) void agg0_kernel(const unsigned* __restrict__ cnt8,
    const float* __restrict__ emb, float* __restrict__ agg) {
  __shared__ float Es[64][64];
  __shared__ float XsT[64][64];
  int t = threadIdx.x;
  int i0 = blockIdx.x * 64;
  int wr = t >> 4, wc = (t & 15) * 4;
  #pragma unroll
  for (int j = 0; j < 4; j++)
    *(float4*)&Es[wr + 16 * j][wc] = *(const float4*)&emb[(long)(wr + 16 * j) * D + wc];
  {
    int row = t & 63;
    int gi = i0 + row;
    int gis = (gi < NN) ? gi : NN - 1;
    int jb = (t >> 6) * 4;
    #pragma unroll
    for (int j = 0; j < 4; j++) {
      unsigned u = cnt8[(long)gis * 16 + jb + j];
      int k = (jb + j) * 4;
      XsT[k + 0][row] = (float)(u & 255);
      XsT[k + 1][row] = (float)((u >> 8) & 255);
      XsT[k + 2][row] = (float)((u >> 16) & 255);
      XsT[k + 3][row] = (float)(u >> 24);
    }
  }
  int c0 = (t & 15) * 4;
  int r0 = (t >> 4) * 4;
  float4 acc[4];
  #pragma unroll
  for (int r = 0; r < 4; r++) acc[r] = make_float4(0.f, 0.f, 0.f, 0.f);
  __syncthreads();
  #pragma unroll 8
  for (int k = 0; k < 64; k++) {
    float4 w4 = *(const float4*)&Es[k][c0];
    float4 x4 = *(const float4*)&XsT[k][r0];
    acc[0].x += x4.x * w4.x; acc[0].y += x4.x * w4.y; acc[0].z += x4.x * w4.z; acc[0].w += x4.x * w4.w;
    acc[1].x += x4.y * w4.x; acc[1].y += x4.y * w4.y; acc[1].z += x4.y * w4.z; acc[1].w += x4.y * w4.w;
    acc[2].x += x4.z * w4.x; acc[2].y += x4.z * w4.y; acc[2].z += x4.z * w4.z; acc[2].w += x4.z * w4.w;
    acc[3].x += x4.w * w4.x; acc[3].y += x4.w * w4.y; acc[3].z += x4.w * w4.z; acc[3].w += x4.w * w4.w;
  }
  #pragma unroll
  for (int r = 0; r < 4; r++) {
    int gi = i0 + r0 + r;
    if (gi < NN) *(float4*)&agg[(long)gi * D + c0] = acc[r];
  }
}

// ---- aggregation (layers 1,2): XCD-pinned fp8 e4m3, 2 slices of 32 dims.
//      slice = blockIdx&1: per-XCD footprint 3.2 MB (fits 4 MB L2);
//      2 line touches per edge (was 4 with bf16 4-slice). ----
__global__ __launch_bounds__(256) void agg_kernel(const int* __restrict__ off,
    const int* __restrict__ srcs, const unsigned* __restrict__ xh32,
    float* __restrict__ agg) {
  int t = threadIdx.x;
  int lane = t & 7;               // 8 lanes x 4 fp8 dims = 32 dims
  int g = t >> 3;                 // 32 node-groups per block
  int b = blockIdx.x;
  int slice = b & 1;
  int i = (b >> 1) * 32 + g;      // 3125 chunks * 32 = 100000 exact
  const unsigned* base = xh32 + (long)slice * NN * 8;  // 32 B/node = 8 uints
  int e0 = off[i], e1 = off[i + 1];
  float s0 = 0.f, s1 = 0.f, s2 = 0.f, s3 = 0.f;
  int e = e0;
  for (; e + 4 <= e1; e += 4) {
    int j0 = srcs[e + 0], j1 = srcs[e + 1], j2 = srcs[e + 2], j3 = srcs[e + 3];
    unsigned u0 = base[(long)j0 * 8 + lane];
    unsigned u1 = base[(long)j1 * 8 + lane];
    unsigned u2 = base[(long)j2 * 8 + lane];
    unsigned u3 = base[(long)j3 * 8 + lane];
    v2f l0 = __builtin_amdgcn_cvt_pk_f32_fp8((int)u0, false);
    v2f h0 = __builtin_amdgcn_cvt_pk_f32_fp8((int)u0, true);
    v2f l1 = __builtin_amdgcn_cvt_pk_f32_fp8((int)u1, false);
    v2f h1 = __builtin_amdgcn_cvt_pk_f32_fp8((int)u1, true);
    v2f l2 = __builtin_amdgcn_cvt_pk_f32_fp8((int)u2, false);
    v2f h2 = __builtin_amdgcn_cvt_pk_f32_fp8((int)u2, true);
    v2f l3 = __builtin_amdgcn_cvt_pk_f32_fp8((int)u3, false);
    v2f h3 = __builtin_amdgcn_cvt_pk_f32_fp8((int)u3, true);
    s0 += (l0.x + l1.x) + (l2.x + l3.x);
    s1 += (l0.y + l1.y) + (l2.y + l3.y);
    s2 += (h0.x + h1.x) + (h2.x + h3.x);
    s3 += (h0.y + h1.y) + (h2.y + h3.y);
  }
  for (; e < e1; e++) {
    unsigned u = base[(long)srcs[e] * 8 + lane];
    v2f lo = __builtin_amdgcn_cvt_pk_f32_fp8((int)u, false);
    v2f hi = __builtin_amdgcn_cvt_pk_f32_fp8((int)u, true);
    s0 += lo.x; s1 += lo.y; s2 += hi.x; s3 += hi.y;
  }
  *(float4*)&agg[(long)i * D + slice * 32 + lane * 4] = make_float4(s0, s1, s2, s3);
}

// ---- fused layer: z = (leaky((a*x+agg)@W1+b1))@W2+b2, + BN partial stats ----
__global__ __launch_bounds__(256) void layer_kernel(
    const float* __restrict__ X,
    const float* __restrict__ AGG,
    const float* __restrict__ epsv, int l,
    const float* __restrict__ W1, const float* __restrict__ b1,
    const float* __restrict__ W2, const float* __restrict__ b2,
    float* __restrict__ Z, float* __restrict__ spread)
{
  __shared__ float Ws[64][64];
  __shared__ float XsT[64][64];
  int t = threadIdx.x;
  int i0 = blockIdx.x * 64;
  float alpha = 1.0f + epsv[l];
  int c0 = (t & 15) * 4;
  int r0 = (t >> 4) * 4;
  int wr = t >> 4;
  int wc = (t & 15) * 4;

  #pragma unroll
  for (int j = 0; j < 4; j++)
    *(float4*)&Ws[wr + 16 * j][wc] = *(const float4*)&W1[(long)(wr + 16 * j) * D + wc];
  {
    int row = t & 63;
    int gi = i0 + row;
    int gis = (gi < NN) ? gi : NN - 1;
    int kb = (t >> 6) * 16;
    #pragma unroll
    for (int j = 0; j < 4; j++) {
      int k = kb + 4 * j;
      float4 xv = *(const float4*)&X[(long)gis * 256 + k];
      float4 a4 = *(const float4*)&AGG[(long)gis * D + k];
      xv.x = alpha * xv.x + a4.x;
      xv.y = alpha * xv.y + a4.y;
      xv.z = alpha * xv.z + a4.z;
      xv.w = alpha * xv.w + a4.w;
      XsT[k + 0][row] = xv.x;
      XsT[k + 1][row] = xv.y;
      XsT[k + 2][row] = xv.z;
      XsT[k + 3][row] = xv.w;
    }
  }
  __syncthreads();

  float4 h[4];
  {
    float4 b4 = *(const float4*)&b1[c0];
    #pragma unroll
    for (int r = 0; r < 4; r++) h[r] = b4;
  }
  #pragma unroll 8
  for (int k = 0; k < 64; k++) {
    float4 w4 = *(const float4*)&Ws[k][c0];
    float4 x4 = *(const float4*)&XsT[k][r0];
    h[0].x += x4.x * w4.x; h[0].y += x4.x * w4.y; h[0].z += x4.x * w4.z; h[0].w += x4.x * w4.w;
    h[1].x += x4.y * w4.x; h[1].y += x4.y * w4.y; h[1].z += x4.y * w4.z; h[1].w += x4.y * w4.w;
    h[2].x += x4.z * w4.x; h[2].y += x4.z * w4.y; h[2].z += x4.z * w4.z; h[2].w += x4.z * w4.w;
    h[3].x += x4.w * w4.x; h[3].y += x4.w * w4.y; h[3].z += x4.w * w4.z; h[3].w += x4.w * w4.w;
  }
  #pragma unroll
  for (int r = 0; r < 4; r++) {
    h[r].x = (h[r].x >= 0.0f) ? h[r].x : 0.01f * h[r].x;
    h[r].y = (h[r].y >= 0.0f) ? h[r].y : 0.01f * h[r].y;
    h[r].z = (h[r].z >= 0.0f) ? h[r].z : 0.01f * h[r].z;
    h[r].w = (h[r].w >= 0.0f) ? h[r].w : 0.01f * h[r].w;
  }
  __syncthreads();

  #pragma unroll
  for (int r = 0; r < 4; r++) {
    XsT[c0 + 0][r0 + r] = h[r].x;
    XsT[c0 + 1][r0 + r] = h[r].y;
    XsT[c0 + 2][r0 + r] = h[r].z;
    XsT[c0 + 3][r0 + r] = h[r].w;
  }
  #pragma unroll
  for (int j = 0; j < 4; j++)
    *(float4*)&Ws[wr + 16 * j][wc] = *(const float4*)&W2[(long)(wr + 16 * j) * D + wc];
  __syncthreads();

  float4 z[4];
  {
    float4 b4 = *(const float4*)&b2[c0];
    #pragma unroll
    for (int r = 0; r < 4; r++) z[r] = b4;
  }
  #pragma unroll 8
  for (int k = 0; k < 64; k++) {
    float4 w4 = *(const float4*)&Ws[k][c0];
    float4 x4 = *(const float4*)&XsT[k][r0];
    z[0].x += x4.x * w4.x; z[0].y += x4.x * w4.y; z[0].z += x4.x * w4.z; z[0].w += x4.x * w4.w;
    z[1].x += x4.y * w4.x; z[1].y += x4.y * w4.y; z[1].z += x4.y * w4.z; z[1].w += x4.y * w4.w;
    z[2].x += x4.z * w4.x; z[2].y += x4.z * w4.y; z[2].z += x4.z * w4.z; z[2].w += x4.z * w4.w;
    z[3].x += x4.w * w4.x; z[3].y += x4.w * w4.y; z[3].z += x4.w * w4.z; z[3].w += x4.w * w4.w;
  }
  #pragma unroll
  for (int r = 0; r < 4; r++) {
    int gi = i0 + r0 + r;
    if (gi < NN) *(float4*)&Z[(long)gi * 256 + c0] = z[r];
  }

  float s[4] = {0, 0, 0, 0}, sq[4] = {0, 0, 0, 0};
  #pragma unroll
  for (int r = 0; r < 4; r++) {
    if (i0 + r0 + r < NN) {
      s[0] += z[r].x; sq[0] += z[r].x * z[r].x;
      s[1] += z[r].y; sq[1] += z[r].y * z[r].y;
      s[2] += z[r].z; sq[2] += z[r].z * z[r].z;
      s[3] += z[r].w; sq[3] += z[r].w * z[r].w;
    }
  }
  __syncthreads();
  float* red = &XsT[0][0];
  int grp = t >> 4;
  #pragma unroll
  for (int j = 0; j < 4; j++) {
    red[grp * 64 + c0 + j] = s[j];
    red[1024 + grp * 64 + c0 + j] = sq[j];
  }
  __syncthreads();
  if (t < 64) {
    float a = 0.0f, b = 0.0f;
    #pragma unroll
    for (int g = 0; g < 16; g++) {
      a += red[g * 64 + t];
      b += red[1024 + g * 64 + t];
    }
    int slot = blockIdx.x & (SPREAD - 1);
    atomicAdd(&spread[slot * 128 + t], a);
    atomicAdd(&spread[slot * 128 + 64 + t], b);
  }
}

// ---- fc1: K=256 gemm + BN partial stats ----
__global__ __launch_bounds__(256) void fc1_kernel(
    const float* __restrict__ X,
    const float* __restrict__ W, const float* __restrict__ bias,
    float* __restrict__ Y, float* __restrict__ spread)
{
  __shared__ float Ws[64][64];
  __shared__ float XsT[64][64];
  int t = threadIdx.x;
  int i0 = blockIdx.x * 64;
  int c0 = (t & 15) * 4;
  int r0 = (t >> 4) * 4;
  int wr = t >> 4;
  int wc = (t & 15) * 4;

  float4 acc[4];
  {
    float4 b4 = *(const float4*)&bias[c0];
    #pragma unroll
    for (int r = 0; r < 4; r++) acc[r] = b4;
  }
  for (int kc = 0; kc < 256; kc += 64) {
    __syncthreads();
    #pragma unroll
    for (int j = 0; j < 4; j++)
      *(float4*)&Ws[wr + 16 * j][wc] = *(const float4*)&W[(long)(kc + wr + 16 * j) * D + wc];
    {
      int row = t & 63;
      int gi = i0 + row;
      int gis = (gi < NN) ? gi : NN - 1;
      int kb = (t >> 6) * 16;
      #pragma unroll
      for (int j = 0; j < 4; j++) {
        int k = kb + 4 * j;
        float4 xv = *(const float4*)&X[(long)gis * 256 + kc + k];
        XsT[k + 0][row] = xv.x;
        XsT[k + 1][row] = xv.y;
        XsT[k + 2][row] = xv.z;
        XsT[k + 3][row] = xv.w;
      }
    }
    __syncthreads();
    #pragma unroll 8
    for (int k = 0; k < 64; k++) {
      float4 w4 = *(const float4*)&Ws[k][c0];
      float4 x4 = *(const float4*)&XsT[k][r0];
      acc[0].x += x4.x * w4.x; acc[0].y += x4.x * w4.y; acc[0].z += x4.x * w4.z; acc[0].w += x4.x * w4.w;
      acc[1].x += x4.y * w4.x; acc[1].y += x4.y * w4.y; acc[1].z += x4.y * w4.z; acc[1].w += x4.y * w4.w;
      acc[2].x += x4.z * w4.x; acc[2].y += x4.z * w4.y; acc[2].z += x4.z * w4.z; acc[2].w += x4.z * w4.w;
      acc[3].x += x4.w * w4.x; acc[3].y += x4.w * w4.y; acc[3].z += x4.w * w4.z; acc[3].w += x4.w * w4.w;
    }
  }
  #pragma unroll
  for (int r = 0; r < 4; r++) {
    int gi = i0 + r0 + r;
    if (gi < NN) *(float4*)&Y[(long)gi * D + c0] = acc[r];
  }
  float s[4] = {0, 0, 0, 0}, sq[4] = {0, 0, 0, 0};
  #pragma unroll
  for (int r = 0; r < 4; r++) {
    if (i0 + r0 + r < NN) {
      s[0] += acc[r].x; sq[0] += acc[r].x * acc[r].x;
      s[1] += acc[r].y; sq[1] += acc[r].y * acc[r].y;
      s[2] += acc[r].z; sq[2] += acc[r].z * acc[r].z;
      s[3] += acc[r].w; sq[3] += acc[r].w * acc[r].w;
    }
  }
  __syncthreads();
  float* red = &XsT[0][0];
  int grp = t >> 4;
  #pragma unroll
  for (int j = 0; j < 4; j++) {
    red[grp * 64 + c0 + j] = s[j];
    red[1024 + grp * 64 + c0 + j] = sq[j];
  }
  __syncthreads();
  if (t < 64) {
    float a = 0.0f, b = 0.0f;
    #pragma unroll
    for (int g = 0; g < 16; g++) {
      a += red[g * 64 + t];
      b += red[1024 + g * 64 + t];
    }
    int slot = blockIdx.x & (SPREAD - 1);
    atomicAdd(&spread[slot * 128 + t], a);
    atomicAdd(&spread[slot * 128 + 64 + t], b);
  }
}

// ---- reduce spread stats -> final [128] ----
__global__ __launch_bounds__(128) void bn_finalize_kernel(
    const float* __restrict__ spread, float* __restrict__ statsF) {
  int t = threadIdx.x;
  float a = 0.0f;
  #pragma unroll
  for (int g = 0; g < SPREAD; g++) a += spread[g * 128 + t];
  statsF[t] = a;
}

// ---- BN apply + leaky (zcat in place) + fp8 e4m3 sliced mirror.
//      Each thread handles a dim-pair (HW packs 2 fp8/instruction). ----
__global__ __launch_bounds__(256) void bn_apply_kernel(float* __restrict__ Zs,
    const float* __restrict__ stats,
    const float* __restrict__ g, const float* __restrict__ b,
    unsigned short* __restrict__ Outh) {
  int idx = blockIdx.x * 256 + threadIdx.x;   // over NN*32 pairs
  int i = idx >> 5, dp = (idx & 31) * 2;      // dims dp, dp+1
  if (i >= NN) return;
  float invn = 1.0f / (float)NN;
  float v0, v1;
  {
    float mu = stats[dp] * invn;
    float var = fmaxf(stats[64 + dp] * invn - mu * mu, 0.0f);
    float sc = g[dp] * rsqrtf(var + BN_EPS);
    v0 = sc * (Zs[(long)i * 256 + dp] - mu) + b[dp];
    v0 = (v0 >= 0.0f) ? v0 : 0.01f * v0;
  }
  {
    float mu = stats[dp + 1] * invn;
    float var = fmaxf(stats[64 + dp + 1] * invn - mu * mu, 0.0f);
    float sc = g[dp + 1] * rsqrtf(var + BN_EPS);
    v1 = sc * (Zs[(long)i * 256 + dp + 1] - mu) + b[dp + 1];
    v1 = (v1 >= 0.0f) ? v1 : 0.01f * v1;
  }
  Zs[(long)i * 256 + dp]     = v0;
  Zs[(long)i * 256 + dp + 1] = v1;
  if (Outh) {
    int packed = __builtin_amdgcn_cvt_pk_fp8_f32(v0, v1, 0, false);
    Outh[(long)(dp >> 5) * NN * 16 + (long)i * 16 + ((dp & 31) >> 1)] =
        (unsigned short)packed;
  }
}

// ---- fused fc BN-apply + fc2 dot + sigmoid ----
__global__ __launch_bounds__(256) void fc2bn_kernel(const float* __restrict__ H,
    const float* __restrict__ stats,
    const float* __restrict__ g, const float* __restrict__ b,
    const float* __restrict__ W2, const float* __restrict__ b2,
    float* __restrict__ out) {
  int tid = threadIdx.x;
  int k = tid & 63, q = tid >> 6;
  int i = blockIdx.x * 4 + q;
  float invn = 1.0f / (float)NN;
  float mu = stats[k] * invn;
  float var = fmaxf(stats[64 + k] * invn - mu * mu, 0.0f);
  float sc = g[k] * rsqrtf(var + BN_EPS);
  float v = 0.0f;
  if (i < NN) {
    float hv = sc * (H[(long)i * D + k] - mu) + b[k];
    hv = (hv >= 0.0f) ? hv : 0.01f * hv;
    v = hv * W2[k];
  }
  #pragma unroll
  for (int off = 32; off > 0; off >>= 1)
    v += __shfl_down(v, off);
  if (k == 0 && i < NN) {
    float x = v + b2[0];
    out[i] = 1.0f / (1.0f + __expf(-x));
  }
}

extern "C" void kernel_launch(void* const* d_in, const int* in_sizes, int n_in,
                              void* d_out, int out_size, void* d_ws, size_t ws_size,
                              hipStream_t stream) {
  const int*   node_deg   = (const int*)d_in[0];
  const int*   edge_index = (const int*)d_in[1];
  const float* embedw     = (const float*)d_in[2];
  const float* eps        = (const float*)d_in[3];
  const float* W1         = (const float*)d_in[4];
  const float* b1         = (const float*)d_in[5];
  const float* W2         = (const float*)d_in[6];
  const float* b2         = (const float*)d_in[7];
  const float* bn_g       = (const float*)d_in[8];
  const float* bn_b       = (const float*)d_in[9];
  const float* fc_W1      = (const float*)d_in[10];
  const float* fc_b1      = (const float*)d_in[11];
  const float* fc_bn_g    = (const float*)d_in[12];
  const float* fc_bn_b    = (const float*)d_in[13];
  const float* fc_W2      = (const float*)d_in[14];
  const float* fc_b2      = (const float*)d_in[15];

  float* zcat   = (float*)d_ws;                 // [N,256]
  float* agg    = zcat + (long)NN * 256;        // [N,64]
  float* statsS = agg + (long)NN * D;           // 4 * SPREAD*128
  float* statsF = statsS + 4 * SPREAD * 128;    // 4 * 128
  int*   csroff = (int*)(statsF + 512);         // [NN+1]
  int*   bsum   = csroff + NN + 1;              // [512]
  int*   csrsrc = bsum + 512;                   // [NE]
  int*   rec    = csrsrc + NE;                  // [NE]
  int*   S      = rec + NE;                     // [NP*392]
  unsigned* cnt8 = (unsigned*)(S + NP * 392);   // [N,16] u32 (byte counts)
  // fp8 mirror [2][N][32] (6.4 MB) overlays rec (dead after sort_kernel)
  unsigned short* xh = (unsigned short*)rec;

  const int rowBlocks  = NN / 4;                 // 25000
  const int gemmBlocks = (NN + 63) / 64;         // 1563
  const int aggBlocks  = (NN / 32) * 2;          // 3125 chunks x 2 slices = 6250
  const int bnBlocks   = (NN * 32 + 255) / 256;  // 12500

  // ---- CSR build + neighbor-degree histogram ----
  bucket_kernel<<<NP, 256, 0, stream>>>(edge_index, rec, S);
  bucketsum_kernel<<<NB, 256, 0, stream>>>(S, bsum);
  scan2_kernel<<<1, 512, 0, stream>>>(bsum);
  sort_kernel<<<NB, 512, 0, stream>>>(rec, S, bsum, node_deg,
      csroff, csrsrc, cnt8);

  hipMemsetAsync(statsS, 0, (size_t)(4 * SPREAD * 128 + 512) * sizeof(float), stream);

  embed_kernel<<<rowBlocks, 256, 0, stream>>>(node_deg, embedw, zcat);

  for (int l = 0; l < 3; ++l) {
    if (l == 0)
      agg0_kernel<<<gemmBlocks, 256, 0, stream>>>(cnt8, embedw, agg);
    else
      agg_kernel<<<aggBlocks, 256, 0, stream>>>(csroff, csrsrc,
          (const unsigned*)xh, agg);
    layer_kernel<<<gemmBlocks, 256, 0, stream>>>(zcat + l * D, agg, eps, l,
        W1 + (long)l * D * D, b1 + (long)l * D,
        W2 + (long)l * D * D, b2 + (long)l * D,
        zcat + (l + 1) * D, statsS + (long)l * SPREAD * 128);
    bn_finalize_kernel<<<1, 128, 0, stream>>>(statsS + (long)l * SPREAD * 128,
        statsF + (long)l * 128);
    bn_apply_kernel<<<bnBlocks, 256, 0, stream>>>(zcat + (l + 1) * D,
        statsF + (long)l * 128, bn_g + (long)l * D, bn_b + (long)l * D,
        (l < 2) ? xh : nullptr);
  }

  fc1_kernel<<<gemmBlocks, 256, 0, stream>>>(zcat, fc_W1, fc_b1, agg,
      statsS + 3L * SPREAD * 128);
  bn_finalize_kernel<<<1, 128, 0, stream>>>(statsS + 3L * SPREAD * 128,
      statsF + 3L * 128);
  fc2bn_kernel<<<rowBlocks, 256, 0, stream>>>(agg, statsF + 3L * 128,
      fc_bn_g, fc_bn_b, fc_W2, fc_b2, (float*)d_out);
}